// Round 10
// baseline (755.559 us; speedup 1.0000x reference)
//
#include <hip/hip_runtime.h>
#include <hip/hip_bf16.h>

typedef __hip_bfloat16 bf16;
typedef __attribute__((ext_vector_type(8))) short bf16x8s;
typedef __attribute__((ext_vector_type(4))) float f32x4;
typedef __attribute__((ext_vector_type(4))) int i32x4;

#define NB 64
#define NS 32
#define NV 10000
#define NE 512
#define NH 512
#define NF 2048
#define ND 1024

static __device__ __forceinline__ float bf2f(bf16 x) { return __bfloat162float(x); }
static __device__ __forceinline__ bf16 f2bf(float x) { return __float2bfloat16(x); }
static __device__ __forceinline__ f32x4 mfma16(bf16x8s a, bf16x8s b, f32x4 c) {
  return __builtin_amdgcn_mfma_f32_16x16x32_bf16(a, b, c, 0, 0, 0);
}

// ---- LLC-coherent (cross-XCD) accesses, bypassing per-XCD L1/L2 via sc0 sc1.
// Compiler does NOT track vmcnt for these — MUST use wait_vm0() (waitcnt +
// sched_barrier, rule #18) before ANY use of the results, including VALU-only use.
static __device__ __forceinline__ i32x4 ld16_sc(const void* p) {
  i32x4 r;
  asm volatile("global_load_dwordx4 %0, %1, off sc0 sc1" : "=v"(r) : "v"(p) : "memory");
  return r;
}
static __device__ __forceinline__ float lddw_sc(const void* p) {
  float r;
  asm volatile("global_load_dword %0, %1, off sc0 sc1" : "=v"(r) : "v"(p) : "memory");
  return r;
}
static __device__ __forceinline__ void st16_sc(void* p, i32x4 v) {
  asm volatile("global_store_dwordx4 %0, %1, off sc0 sc1" :: "v"(p), "v"(v) : "memory");
}
static __device__ __forceinline__ void stud_sc(void* p, unsigned v) {
  asm volatile("global_store_dword %0, %1, off sc0 sc1" :: "v"(p), "v"(v) : "memory");
}
static __device__ __forceinline__ void wait_vm0() {
  asm volatile("s_waitcnt vmcnt(0)" ::: "memory");
  __builtin_amdgcn_sched_barrier(0);   // rule #18: pin consumers after the wait
}
static __device__ __forceinline__ unsigned min4u(i32x4 a) {
  return min(min((unsigned)a[0], (unsigned)a[1]), min((unsigned)a[2], (unsigned)a[3]));
}

// One 16x16 output tile per wave (cached path, plain GEMMs).
__device__ __forceinline__ f32x4 wave_tile16(const bf16* A, const bf16* BT,
                                             int lda, int K, int m0, int n0) {
  int lane = threadIdx.x & 63;
  int r = lane & 15, g = lane >> 4;
  const bf16* ap = A + (size_t)(m0 + r) * lda + g * 8;
  const bf16* bp = BT + (size_t)(n0 + r) * K + g * 8;
  f32x4 acc = {0.f, 0.f, 0.f, 0.f};
#pragma unroll 4
  for (int k = 0; k < K; k += 32) {
    bf16x8s a = *(const bf16x8s*)(ap + k);
    bf16x8s b = *(const bf16x8s*)(bp + k);
    acc = mfma16(a, b, acc);
  }
  return acc;
}

// ---------------- embedding gather + f32->bf16 ; x0 layout [t][b][512] ----------------
__global__ void k_embed(const int* __restrict__ tokens, const float* __restrict__ emb,
                        bf16* __restrict__ x0) {
  int row = blockIdx.x;              // = b*32 + t
  int tok = tokens[row];
  int drow = (row & 31) * 64 + (row >> 5);     // [t][b]
  const float2* src = (const float2*)(emb + (size_t)tok * NE);
  uint32_t* dst = (uint32_t*)(x0 + (size_t)drow * NE);
  float2 v = src[threadIdx.x];
  __hip_bfloat162 p;
  p.x = f2bf(v.x); p.y = f2bf(v.y);
  dst[threadIdx.x] = *(uint32_t*)&p;
}

__global__ void k_cvt(const float* __restrict__ src, bf16* __restrict__ dst, int n) {
  int i = blockIdx.x * 256 + threadIdx.x;
  if (i < n) dst[i] = f2bf(src[i]);
}

__global__ void k_transpose(const float* __restrict__ src, bf16* __restrict__ dst,
                            int K, int N) {
  __shared__ float tile[32][33];
  int n0 = blockIdx.x * 32, k0 = blockIdx.y * 32;
  int tx = threadIdx.x & 31, ty = threadIdx.x >> 5;
  for (int i = ty; i < 32; i += 8) {
    int k = k0 + i, n = n0 + tx;
    tile[i][tx] = (k < K && n < N) ? src[(size_t)k * N + n] : 0.f;
  }
  __syncthreads();
  for (int i = ty; i < 32; i += 8) {
    int n = n0 + i, k = k0 + tx;
    if (n < N && k < K) dst[(size_t)n * K + k] = f2bf(tile[tx][i]);
  }
}

__global__ void k_transpose12(const float* __restrict__ w_r, const float* __restrict__ w_u,
                              const float* __restrict__ w_h, bf16* __restrict__ ruhT,
                              bf16* __restrict__ hhT, bf16* __restrict__ xT) {
  int z = blockIdx.z, l = z / 6, q = z % 6;
  const float* srcs[6] = {
    w_r + (size_t)l * ND * NH + (size_t)512 * NH,
    w_u + (size_t)l * ND * NH + (size_t)512 * NH,
    w_h + (size_t)l * ND * NH + (size_t)512 * NH,
    w_r + (size_t)l * ND * NH,
    w_u + (size_t)l * ND * NH,
    w_h + (size_t)l * ND * NH };
  bf16* dsts[6] = {
    ruhT + (size_t)l * 1024 * 512,
    ruhT + (size_t)l * 1024 * 512 + 512 * 512,
    hhT  + (size_t)l * 512 * 512,
    xT   + (size_t)l * 1536 * 512,
    xT   + (size_t)l * 1536 * 512 + 512 * 512,
    xT   + (size_t)l * 1536 * 512 + 1024 * 512 };
  const float* src = srcs[q];
  bf16* dst = dsts[q];
  __shared__ float tile[32][33];
  int n0 = blockIdx.x * 32, k0 = blockIdx.y * 32;
  int tx = threadIdx.x & 31, ty = threadIdx.x >> 5;
  for (int i = ty; i < 32; i += 8)
    tile[i][tx] = src[(size_t)(k0 + i) * NH + n0 + tx];
  __syncthreads();
  for (int i = ty; i < 32; i += 8)
    dst[(size_t)(n0 + i) * NH + k0 + tx] = f2bf(tile[tx][i]);
}

__global__ void k_bias3all(const float* __restrict__ br, const float* __restrict__ bu,
                           const float* __restrict__ bh, float* __restrict__ bias) {
  int i = blockIdx.x * 256 + threadIdx.x;
  if (i < 3072) {
    int l = i / 1536, c = i % 1536;
    const float* s = (c < 512) ? (br + l * 512 + c)
                   : (c < 1024 ? (bu + l * 512 + (c - 512)) : (bh + l * 512 + (c - 1024)));
    bias[i] = *s;
  }
}

// ---------------- h0 = cnn @ w_in + b_in, dual-store f32 + bf16 ----------------
__global__ void k_gemm_h0(const bf16* __restrict__ A, const bf16* __restrict__ BT,
                          const float* __restrict__ bias,
                          float* __restrict__ h0f, bf16* __restrict__ h0b) {
  int wid = blockIdx.x * 4 + (threadIdx.x >> 6);
  int mt = wid & 3, nt = wid >> 2;
  f32x4 acc = wave_tile16(A, BT, NF, NF, mt * 16, nt * 16);
  int lane = threadIdx.x & 63;
  int cl = lane & 15, g = lane >> 4;
  int col = nt * 16 + cl;
  float bv = bias[col];
#pragma unroll
  for (int j = 0; j < 4; j++) {
    int row = mt * 16 + g * 4 + j;
    float v = acc[j] + bv;
    h0f[(size_t)row * NH + col] = v;
    h0b[(size_t)row * NH + col] = f2bf(v);
  }
}

// ---------------- fused persistent 2-layer GRU, group-multiplexed ----------------
// 144 WGs x 512 thr, 1 WG/CU. WGs 0..15: recurrence (layer l=bid>>3, col-octant
// o=bid&7); each WG serves ALL 4 batch-groups per step (handoff latency hides behind
// sibling groups). Waves 0-3: r + h_tilde (W_r,W_h resident); waves 4-7: u (W_u).
// WGs 16..143: pre-workers filling an 8-slot pre ring = x(t)@Wx+b; layer1's x(t) =
// layer0's h(t). All cross-WG data via sc0sc1 (LLC) + monotonic flags. Every flag
// poll drains vmcnt and sched-barriers BEFORE reading the loaded registers (#18).
__global__ __launch_bounds__(512, 1)
void k_fused(const bf16* __restrict__ w_ruh, const bf16* __restrict__ w_hh,
             const bf16* __restrict__ w_x, const float* __restrict__ bias3,
             const float* __restrict__ h0f, const bf16* __restrict__ h0b,
             const bf16* __restrict__ x0, bf16* __restrict__ seq0,
             bf16* __restrict__ seq1, bf16* __restrict__ rh_buf,
             float* __restrict__ pre, unsigned* __restrict__ flags) {
  __shared__ char lds[98304];
  const int tid = threadIdx.x;
  const int lane = tid & 63;
  const int wv = tid >> 6;
  const int cl = lane & 15, l4 = lane >> 4;
  const int bid = blockIdx.x;
  const int in0 = lane * 16;                 // staging: lane-contiguous 16B
  const int dsw = in0 ^ (wv << 4);           // (row&7)<<4 swizzle, row = wv or wv+8

  auto poll32 = [&](const unsigned* f, unsigned tgt) {
    if (tid == 0) {
      for (;;) {
        i32x4 a0 = ld16_sc(f),      a1 = ld16_sc(f + 4),  a2 = ld16_sc(f + 8),
              a3 = ld16_sc(f + 12), a4 = ld16_sc(f + 16), a5 = ld16_sc(f + 20),
              a6 = ld16_sc(f + 24), a7 = ld16_sc(f + 28);
        wait_vm0();                                          // #18: BEFORE min
        unsigned mn = min(min(min(min4u(a0), min4u(a1)), min(min4u(a2), min4u(a3))),
                          min(min(min4u(a4), min4u(a5)), min(min4u(a6), min4u(a7))));
        if (mn >= tgt) break;
        __builtin_amdgcn_s_sleep(1);
      }
    }
    __syncthreads();
    __builtin_amdgcn_sched_barrier(0);
  };
  auto poll8 = [&](const unsigned* f, unsigned tgt) {
    if (tid == 0) {
      for (;;) {
        i32x4 a0 = ld16_sc(f), a1 = ld16_sc(f + 4);
        wait_vm0();                                          // #18
        if (min(min4u(a0), min4u(a1)) >= tgt) break;
        __builtin_amdgcn_s_sleep(1);
      }
    }
    __syncthreads();
    __builtin_amdgcn_sched_barrier(0);
  };

  if (bid < 16) {
    // ================= recurrence =================
    const int l = bid >> 3, o = bid & 7;
    const bool is_u = (wv >= 4);
    const int wsub = wv & 3;
    const int c = o * 64 + wsub * 16 + cl;             // own col 0..511
    const int cA = is_u ? 512 + c : c;
    char* hpan = lds;                                   // 4 x 16KB (reused for rh)
    float* ul = (float*)(lds + 65536);                  // [g][wsub][16][16] f32
    char* rout = lds + 81920;                           // [g][16][64] bf16
    char* hout = lds + 90112;                           // [g][16][64] bf16
    unsigned* fh   = flags + l * 32;                    // + g*8 + o
    unsigned* frh  = flags + 64 + l * 32;
    bf16* seql = l ? seq1 : seq0;

    bf16x8s bwA[16];
    { const bf16* p = w_ruh + (size_t)l * 1024 * 512 + (size_t)cA * 512 + l4 * 8;
#pragma unroll
      for (int kk = 0; kk < 16; kk++) bwA[kk] = *(const bf16x8s*)(p + kk * 32); }
    bf16x8s bwB[16];
    float h_reg[4][4];
    if (!is_u) {
      const bf16* p = w_hh + (size_t)l * 512 * 512 + (size_t)c * 512 + l4 * 8;
#pragma unroll
      for (int kk = 0; kk < 16; kk++) bwB[kk] = *(const bf16x8s*)(p + kk * 32);
#pragma unroll
      for (int g = 0; g < 4; g++)
#pragma unroll
        for (int j = 0; j < 4; j++)
          h_reg[g][j] = h0f[(size_t)(g * 16 + l4 * 4 + j) * 512 + c];
    }

    // stage 4 x 16KB contiguous slabs -> swizzled panels (wave-per-row, conflict-free)
    auto stage4 = [&](const char* s) {
      i32x4 v[8];
#pragma unroll
      for (int g = 0; g < 4; g++) {
        v[g * 2]     = ld16_sc(s + g * 16384 + (size_t)wv * 1024 + in0);
        v[g * 2 + 1] = ld16_sc(s + g * 16384 + (size_t)(wv + 8) * 1024 + in0);
      }
      wait_vm0();
#pragma unroll
      for (int g = 0; g < 4; g++) {
        *(i32x4*)(hpan + g * 16384 + wv * 1024 + dsw) = v[g * 2];
        *(i32x4*)(hpan + g * 16384 + (wv + 8) * 1024 + dsw) = v[g * 2 + 1];
      }
    };

#pragma unroll 1
    for (int t = 0; t < NS; t++) {
      if (t) poll32(fh, (unsigned)t);                            // h(t-1) all groups
      poll32(flags + 128 + (l * 2 + (t & 1)) * 32, (unsigned)((t >> 1) + 1));  // pre(t)
      stage4(t == 0 ? (const char*)h0b
                    : (const char*)seql + (size_t)(t - 1) * 64 * 1024);
      __syncthreads();
      // ---- phase 1: batched pre loads, then 64 MFMAs, one drain
      const float* pb0 = pre + (size_t)(l * 8 + (t & 7)) * 64 * 1536;
      float pA[4][4];
#pragma unroll
      for (int g = 0; g < 4; g++)
#pragma unroll
        for (int j = 0; j < 4; j++)
          pA[g][j] = lddw_sc(pb0 + (size_t)(g * 16 + l4 * 4 + j) * 1536 + cA);
      f32x4 accg[4];
#pragma unroll
      for (int g = 0; g < 4; g++) {
        const char* pan = hpan + g * 16384;
        f32x4 acc = {0.f, 0.f, 0.f, 0.f};
#pragma unroll
        for (int kk = 0; kk < 16; kk++)
          acc = mfma16(*(const bf16x8s*)(pan + cl * 1024 + ((kk * 64 + l4 * 16) ^ ((cl & 7) << 4))),
                       bwA[kk], acc);
        accg[g] = acc;
      }
      wait_vm0();
#pragma unroll
      for (int g = 0; g < 4; g++) {
#pragma unroll
        for (int j = 0; j < 4; j++) {
          float gate = 1.f / (1.f + expf(-(accg[g][j] + pA[g][j])));
          int row = l4 * 4 + j;
          if (is_u) {
            ul[((g * 4 + wsub) * 16 + row) * 16 + cl] = gate;
          } else {
            int c2 = c * 2;
            unsigned short hv = *(const unsigned short*)
              (hpan + g * 16384 + row * 1024 + ((c2 & ~15) ^ ((row & 7) << 4)) + (c2 & 15));
            bf16 hb_ = *(bf16*)&hv;
            bf16 rhv = f2bf(gate * bf2f(hb_));
            *(unsigned short*)(rout + g * 2048 + row * 128 + (wsub * 16 + cl) * 2)
              = *(unsigned short*)&rhv;
          }
        }
      }
      __syncthreads();
      { // ---- publish rh slices (coalesced 16B sc-stores)
        int gg = tid >> 7, i = tid & 127, prow = i >> 3, pch = i & 7;
        i32x4 v = *(i32x4*)(rout + gg * 2048 + prow * 128 + pch * 16);
        st16_sc((char*)rh_buf + (((size_t)(l * 4 + gg) * 16 + prow) * 512 + o * 64 + pch * 8) * 2, v);
      }
      wait_vm0();
      __syncthreads();
      if (tid == 0) {
#pragma unroll
        for (int g = 0; g < 4; g++) stud_sc(&frh[g * 8 + o], (unsigned)(t + 1));
      }
      poll32(frh, (unsigned)(t + 1));
      stage4((const char*)rh_buf + (size_t)l * 4 * 16 * 1024);
      __syncthreads();
      // ---- phase 2: h_tilde + combine (waves 0-3)
      if (!is_u) {
        float px[4][4];
#pragma unroll
        for (int g = 0; g < 4; g++)
#pragma unroll
          for (int j = 0; j < 4; j++)
            px[g][j] = lddw_sc(pb0 + (size_t)(g * 16 + l4 * 4 + j) * 1536 + 1024 + c);
        f32x4 acc2[4];
#pragma unroll
        for (int g = 0; g < 4; g++) {
          const char* pan = hpan + g * 16384;
          f32x4 acc = {0.f, 0.f, 0.f, 0.f};
#pragma unroll
          for (int kk = 0; kk < 16; kk++)
            acc = mfma16(*(const bf16x8s*)(pan + cl * 1024 + ((kk * 64 + l4 * 16) ^ ((cl & 7) << 4))),
                         bwB[kk], acc);
          acc2[g] = acc;
        }
        wait_vm0();
#pragma unroll
        for (int g = 0; g < 4; g++) {
#pragma unroll
          for (int j = 0; j < 4; j++) {
            int row = l4 * 4 + j;
            float htil = tanhf(acc2[g][j] + px[g][j]);
            float u = ul[((g * 4 + wsub) * 16 + row) * 16 + cl];
            float hnew = h_reg[g][j] * u + (1.f - u) * htil;
            h_reg[g][j] = hnew;
            bf16 hn = f2bf(hnew);
            *(unsigned short*)(hout + g * 2048 + row * 128 + (wsub * 16 + cl) * 2)
              = *(unsigned short*)&hn;
          }
        }
      }
      __syncthreads();
      { // ---- publish h slices into seq[l] ([t][b][col] contiguous slab)
        int gg = tid >> 7, i = tid & 127, prow = i >> 3, pch = i & 7;
        i32x4 v = *(i32x4*)(hout + gg * 2048 + prow * 128 + pch * 16);
        st16_sc((char*)seql + (((size_t)t * 64 + gg * 16 + prow) * 512 + o * 64 + pch * 8) * 2, v);
      }
      wait_vm0();
      __syncthreads();
      if (tid == 0) {
#pragma unroll
        for (int g = 0; g < 4; g++) stud_sc(&fh[g * 8 + o], (unsigned)(t + 1));
      }
    }
  } else {
    // ================= pre-worker =================
    const int wb = bid - 16;
    const int l = wb >> 6, r6 = wb & 63, g = r6 >> 4, q = r6 & 15, cs = q >> 1, p = q & 1;
    char* xpan = lds;
    const int ct0 = cs * 12 + wv;                      // < 96
    const int ct1 = cs * 12 + 8 + wv;                  // valid when wv < 4
    const bf16* xsrc = l ? seq0 : x0;
    float* prel = pre + (size_t)l * 8 * 64 * 1536;
    unsigned* fh0g = flags + 0 * 32 + g * 8;           // layer0 h flags (x gating)
    unsigned* fhlg = flags + l * 32 + g * 8;           // own-layer h flags (ring gate)
    unsigned* fpw  = flags + 128 + (l * 2 + p) * 32 + g * 8;

    bf16x8s wx0[16], wx1[16];
    { const bf16* pw = w_x + (size_t)l * 1536 * 512 + (size_t)(ct0 * 16 + cl) * 512 + l4 * 8;
#pragma unroll
      for (int kk = 0; kk < 16; kk++) wx0[kk] = *(const bf16x8s*)(pw + kk * 32); }
    if (wv < 4) {
      const bf16* pw = w_x + (size_t)l * 1536 * 512 + (size_t)(ct1 * 16 + cl) * 512 + l4 * 8;
#pragma unroll
      for (int kk = 0; kk < 16; kk++) wx1[kk] = *(const bf16x8s*)(pw + kk * 32);
    }
    const float b0 = bias3[l * 1536 + ct0 * 16 + cl];
    const float b1 = (wv < 4) ? bias3[l * 1536 + ct1 * 16 + cl] : 0.f;

#pragma unroll 1
    for (int tt = 0; tt < 16; tt++) {
      const int t = tt * 2 + p;
      if (l == 1) poll8(fh0g, (unsigned)(t + 1));      // x(t) = layer0 h(t)
      if (t >= 8) poll8(fhlg, (unsigned)(t - 7));      // ring-overwrite gate
      { // stage one 16KB x slab (conflict-free)
        const char* s = (const char*)xsrc + ((size_t)t * 64 + g * 16) * 1024;
        i32x4 v0 = ld16_sc(s + (size_t)wv * 1024 + in0);
        i32x4 v1 = ld16_sc(s + (size_t)(wv + 8) * 1024 + in0);
        wait_vm0();
        *(i32x4*)(xpan + wv * 1024 + dsw) = v0;
        *(i32x4*)(xpan + (wv + 8) * 1024 + dsw) = v1;
      }
      __syncthreads();
      f32x4 c0 = {0.f, 0.f, 0.f, 0.f}, c1 = {0.f, 0.f, 0.f, 0.f};
#pragma unroll
      for (int kk = 0; kk < 16; kk++) {
        bf16x8s a = *(const bf16x8s*)(xpan + cl * 1024 + ((kk * 64 + l4 * 16) ^ ((cl & 7) << 4)));
        c0 = mfma16(a, wx0[kk], c0);
        if (wv < 4) c1 = mfma16(a, wx1[kk], c1);
      }
      float* pdst = prel + ((size_t)(t & 7) * 64 + g * 16) * 1536;
#pragma unroll
      for (int j = 0; j < 4; j++) {
        union { float f; unsigned u; } cv;
        cv.f = c0[j] + b0;
        stud_sc(pdst + (l4 * 4 + j) * 1536 + ct0 * 16 + cl, cv.u);
      }
      if (wv < 4) {
#pragma unroll
        for (int j = 0; j < 4; j++) {
          union { float f; unsigned u; } cv;
          cv.f = c1[j] + b1;
          stud_sc(pdst + (l4 * 4 + j) * 1536 + ct1 * 16 + cl, cv.u);
        }
      }
      wait_vm0();
      __syncthreads();
      if (tid == 0) stud_sc(&fpw[cs], (unsigned)(tt + 1));
    }
  }
}

// ---------------- logits: out[b*32+t][v] = seq1[t][b][:] @ w_out + b_out ----------------
__global__ void k_gemm_out(const bf16* __restrict__ A, const bf16* __restrict__ BT,
                           const float* __restrict__ bias, float* __restrict__ out) {
  int wid = blockIdx.x * 4 + (threadIdx.x >> 6);
  int mg = wid % 32, ng = wid / 32;
  int lane = threadIdx.x & 63;
  int cl = lane & 15, g = lane >> 4;
  f32x4 acc[4][4] = {};
  // A row r = mg*64 + mi*16 + cl  ->  seq row ((mi&1)*16+cl)*64 + mg*2 + (mi>>1)
  const bf16* arow[4];
#pragma unroll
  for (int mi = 0; mi < 4; mi++)
    arow[mi] = A + ((size_t)(((mi & 1) * 16 + cl)) * 64 + mg * 2 + (mi >> 1)) * NE + g * 8;
  const bf16* b0 = BT + (size_t)(ng * 64 + cl) * NE + g * 8;
  bf16x8s av[2][4], bv[2][4];
#pragma unroll
  for (int i = 0; i < 4; i++) {
    av[0][i] = *(const bf16x8s*)(arow[i]);
    bv[0][i] = *(const bf16x8s*)(b0 + (size_t)(i * 16) * NE);
  }
#pragma unroll
  for (int ks = 0; ks < 16; ks++) {
    const int cur = ks & 1;
    if (ks < 15) {
#pragma unroll
      for (int i = 0; i < 4; i++) {
        av[cur ^ 1][i] = *(const bf16x8s*)(arow[i] + (ks + 1) * 32);
        bv[cur ^ 1][i] = *(const bf16x8s*)(b0 + (size_t)(i * 16) * NE + (ks + 1) * 32);
      }
    }
#pragma unroll
    for (int mi = 0; mi < 4; mi++)
#pragma unroll
      for (int ni = 0; ni < 4; ni++)
        acc[mi][ni] = mfma16(av[cur][mi], bv[cur][ni], acc[mi][ni]);
  }
#pragma unroll
  for (int mi = 0; mi < 4; mi++) {
#pragma unroll
    for (int ni = 0; ni < 4; ni++) {
      int colb = ng * 64 + ni * 16 + cl;
      if (colb < NV) {
        float bv2 = bias[colb];
#pragma unroll
        for (int j = 0; j < 4; j++) {
          int row = mg * 64 + mi * 16 + g * 4 + j;
          out[(size_t)row * NV + colb] = acc[mi][ni][j] + bv2;
        }
      }
    }
  }
}

extern "C" void kernel_launch(void* const* d_in, const int* in_sizes, int n_in,
                              void* d_out, int out_size, void* d_ws, size_t ws_size,
                              hipStream_t stream) {
  const int*   tokens = (const int*)d_in[0];
  const float* cnn    = (const float*)d_in[1];
  const float* emb    = (const float*)d_in[2];
  const float* w_in   = (const float*)d_in[3];
  const float* b_in   = (const float*)d_in[4];
  const float* w_r    = (const float*)d_in[5];
  const float* b_r    = (const float*)d_in[6];
  const float* w_u    = (const float*)d_in[7];
  const float* b_u    = (const float*)d_in[8];
  const float* w_h    = (const float*)d_in[9];
  const float* b_h    = (const float*)d_in[10];
  const float* w_out  = (const float*)d_in[11];
  const float* b_out  = (const float*)d_in[12];
  float* out = (float*)d_out;

  char* ws = (char*)d_ws;
  size_t off = 0;
  auto alloc = [&](size_t bytes) { char* p = ws + off; off += (bytes + 255) & ~(size_t)255; return p; };
  bf16*  x0      = (bf16*) alloc((size_t)2048 * 512 * 2);          // [t][b][512]
  bf16*  seq0    = (bf16*) alloc((size_t)2048 * 512 * 2);          // [t][b][512]
  bf16*  seq1    = (bf16*) alloc((size_t)2048 * 512 * 2);          // [t][b][512]
  float* pre     = (float*)alloc((size_t)2 * 8 * 64 * 1536 * 4);   // ring
  float* h0f     = (float*)alloc((size_t)64 * 512 * 4);
  bf16*  h0b     = (bf16*) alloc((size_t)64 * 512 * 2);
  bf16*  rh_buf  = (bf16*) alloc((size_t)2 * 4 * 16 * 512 * 2);
  float* bias3   = (float*)alloc((size_t)2 * 1536 * 4);
  bf16*  cnn_b   = (bf16*) alloc((size_t)64 * 2048 * 2);
  bf16*  w_in_T  = (bf16*) alloc((size_t)512 * 2048 * 2);
  bf16*  w_ruh_T = (bf16*) alloc((size_t)2 * 1024 * 512 * 2);
  bf16*  w_hh_T  = (bf16*) alloc((size_t)2 * 512 * 512 * 2);
  bf16*  w_x_T   = (bf16*) alloc((size_t)2 * 1536 * 512 * 2);
  bf16*  w_out_T = (bf16*) alloc((size_t)10048 * 512 * 2);
  unsigned* flags = (unsigned*)alloc(1024);   // 256 dwords
  (void)ws_size; (void)in_sizes; (void)n_in; (void)out_size;

  hipMemsetAsync(flags, 0, 1024, stream);
  hipMemsetAsync(w_out_T + (size_t)10000 * 512, 0, (size_t)48 * 512 * 2, stream);

  k_embed<<<2048, 256, 0, stream>>>(tokens, emb, x0);
  k_cvt<<<512, 256, 0, stream>>>(cnn, cnn_b, 64 * 2048);
  k_transpose<<<dim3(16, 64), 256, 0, stream>>>(w_in, w_in_T, NF, NH);
  k_transpose12<<<dim3(16, 16, 12), 256, 0, stream>>>(w_r, w_u, w_h, w_ruh_T, w_hh_T, w_x_T);
  k_transpose<<<dim3(313, 16), 256, 0, stream>>>(w_out, w_out_T, 512, NV);
  k_bias3all<<<12, 256, 0, stream>>>(b_r, b_u, b_h, bias3);

  k_gemm_h0<<<32, 256, 0, stream>>>(cnn_b, w_in_T, b_in, h0f, h0b);

  k_fused<<<144, 512, 0, stream>>>(w_ruh_T, w_hh_T, w_x_T, bias3, h0f, h0b,
                                   x0, seq0, seq1, rh_buf, pre, flags);

  k_gemm_out<<<1256, 256, 0, stream>>>(seq1, w_out_T, b_out, out);
}

// Round 11
// 442.915 us; speedup vs baseline: 1.7059x; 1.7059x over previous
//
#include <hip/hip_runtime.h>
#include <hip/hip_bf16.h>

typedef __hip_bfloat16 bf16;
typedef __attribute__((ext_vector_type(8))) short bf16x8s;
typedef __attribute__((ext_vector_type(4))) float f32x4;
typedef __attribute__((ext_vector_type(4))) int i32x4;

#define NB 64
#define NS 32
#define NV 10000
#define NE 512
#define NH 512
#define NF 2048
#define ND 1024

static __device__ __forceinline__ float bf2f(bf16 x) { return __bfloat162float(x); }
static __device__ __forceinline__ bf16 f2bf(float x) { return __float2bfloat16(x); }
static __device__ __forceinline__ f32x4 mfma16(bf16x8s a, bf16x8s b, f32x4 c) {
  return __builtin_amdgcn_mfma_f32_16x16x32_bf16(a, b, c, 0, 0, 0);
}

// ---- LLC-coherent (cross-XCD) accesses, bypassing per-XCD L1/L2 via sc0 sc1.
// Compiler does NOT track vmcnt for these — MUST wait_vm0() (waitcnt+sched_barrier,
// rule #18) before ANY use of results, including register-only VALU use.
static __device__ __forceinline__ i32x4 ld16_sc(const void* p) {
  i32x4 r;
  asm volatile("global_load_dwordx4 %0, %1, off sc0 sc1" : "=v"(r) : "v"(p) : "memory");
  return r;
}
static __device__ __forceinline__ void st16_sc(void* p, i32x4 v) {
  asm volatile("global_store_dwordx4 %0, %1, off sc0 sc1" :: "v"(p), "v"(v) : "memory");
}
static __device__ __forceinline__ void stud_sc(void* p, unsigned v) {
  asm volatile("global_store_dword %0, %1, off sc0 sc1" :: "v"(p), "v"(v) : "memory");
}
static __device__ __forceinline__ void wait_vm0() {
  asm volatile("s_waitcnt vmcnt(0)" ::: "memory");
  __builtin_amdgcn_sched_barrier(0);
}
static __device__ __forceinline__ unsigned min4u(i32x4 a) {
  return min(min((unsigned)a[0], (unsigned)a[1]), min((unsigned)a[2], (unsigned)a[3]));
}

// One 16x16 output tile per wave (cached path, plain GEMMs).
__device__ __forceinline__ f32x4 wave_tile16(const bf16* A, const bf16* BT,
                                             int lda, int K, int m0, int n0) {
  int lane = threadIdx.x & 63;
  int r = lane & 15, g = lane >> 4;
  const bf16* ap = A + (size_t)(m0 + r) * lda + g * 8;
  const bf16* bp = BT + (size_t)(n0 + r) * K + g * 8;
  f32x4 acc = {0.f, 0.f, 0.f, 0.f};
#pragma unroll 4
  for (int k = 0; k < K; k += 32) {
    bf16x8s a = *(const bf16x8s*)(ap + k);
    bf16x8s b = *(const bf16x8s*)(bp + k);
    acc = mfma16(a, b, acc);
  }
  return acc;
}

// ---------------- embedding gather + f32->bf16 ([b*S+t][512]) ----------------
__global__ void k_embed(const int* __restrict__ tokens, const float* __restrict__ emb,
                        bf16* __restrict__ x0) {
  int row = blockIdx.x;
  int tok = tokens[row];
  const float2* src = (const float2*)(emb + (size_t)tok * NE);
  uint32_t* dst = (uint32_t*)(x0 + (size_t)row * NE);
  float2 v = src[threadIdx.x];
  __hip_bfloat162 p;
  p.x = f2bf(v.x); p.y = f2bf(v.y);
  dst[threadIdx.x] = *(uint32_t*)&p;
}

__global__ void k_cvt(const float* __restrict__ src, bf16* __restrict__ dst, int n) {
  int i = blockIdx.x * 256 + threadIdx.x;
  if (i < n) dst[i] = f2bf(src[i]);
}

__global__ void k_transpose(const float* __restrict__ src, bf16* __restrict__ dst,
                            int K, int N) {
  __shared__ float tile[32][33];
  int n0 = blockIdx.x * 32, k0 = blockIdx.y * 32;
  int tx = threadIdx.x & 31, ty = threadIdx.x >> 5;
  for (int i = ty; i < 32; i += 8) {
    int k = k0 + i, n = n0 + tx;
    tile[i][tx] = (k < K && n < N) ? src[(size_t)k * N + n] : 0.f;
  }
  __syncthreads();
  for (int i = ty; i < 32; i += 8) {
    int n = n0 + i, k = k0 + tx;
    if (n < N && k < K) dst[(size_t)n * K + k] = f2bf(tile[tx][i]);
  }
}

__global__ void k_transpose12(const float* __restrict__ w_r, const float* __restrict__ w_u,
                              const float* __restrict__ w_h, bf16* __restrict__ ruhT,
                              bf16* __restrict__ hhT, bf16* __restrict__ xT) {
  int z = blockIdx.z, l = z / 6, q = z % 6;
  const float* srcs[6] = {
    w_r + (size_t)l * ND * NH + (size_t)512 * NH,
    w_u + (size_t)l * ND * NH + (size_t)512 * NH,
    w_h + (size_t)l * ND * NH + (size_t)512 * NH,
    w_r + (size_t)l * ND * NH,
    w_u + (size_t)l * ND * NH,
    w_h + (size_t)l * ND * NH };
  bf16* dsts[6] = {
    ruhT + (size_t)l * 1024 * 512,
    ruhT + (size_t)l * 1024 * 512 + 512 * 512,
    hhT  + (size_t)l * 512 * 512,
    xT   + (size_t)l * 1536 * 512,
    xT   + (size_t)l * 1536 * 512 + 512 * 512,
    xT   + (size_t)l * 1536 * 512 + 1024 * 512 };
  const float* src = srcs[q];
  bf16* dst = dsts[q];
  __shared__ float tile[32][33];
  int n0 = blockIdx.x * 32, k0 = blockIdx.y * 32;
  int tx = threadIdx.x & 31, ty = threadIdx.x >> 5;
  for (int i = ty; i < 32; i += 8)
    tile[i][tx] = src[(size_t)(k0 + i) * NH + n0 + tx];
  __syncthreads();
  for (int i = ty; i < 32; i += 8)
    dst[(size_t)(n0 + i) * NH + k0 + tx] = f2bf(tile[tx][i]);
}

__global__ void k_bias3all(const float* __restrict__ br, const float* __restrict__ bu,
                           const float* __restrict__ bh, float* __restrict__ bias) {
  int i = blockIdx.x * 256 + threadIdx.x;
  if (i < 3072) {
    int l = i / 1536, c = i % 1536;
    const float* s = (c < 512) ? (br + l * 512 + c)
                   : (c < 1024 ? (bu + l * 512 + (c - 512)) : (bh + l * 512 + (c - 1024)));
    bias[i] = *s;
  }
}

// ---------------- h0 = cnn @ w_in + b_in, dual-store f32 + bf16 ----------------
__global__ void k_gemm_h0(const bf16* __restrict__ A, const bf16* __restrict__ BT,
                          const float* __restrict__ bias,
                          float* __restrict__ h0f, bf16* __restrict__ h0b) {
  int wid = blockIdx.x * 4 + (threadIdx.x >> 6);
  int mt = wid & 3, nt = wid >> 2;
  f32x4 acc = wave_tile16(A, BT, NF, NF, mt * 16, nt * 16);
  int lane = threadIdx.x & 63;
  int cl = lane & 15, g = lane >> 4;
  int col = nt * 16 + cl;
  float bv = bias[col];
#pragma unroll
  for (int j = 0; j < 4; j++) {
    int row = mt * 16 + g * 4 + j;
    float v = acc[j] + bv;
    h0f[(size_t)row * NH + col] = v;
    h0b[(size_t)row * NH + col] = f2bf(v);
  }
}

// ---------------- fused 2-layer persistent GRU (R7 structure) ----------------
// 64 WGs x 512 thr: layer = bid>>5, group mt = bid&3 (batches mt*16..+15),
// ng = (bid&31)>>2 (cols ng*64..+64). x-GEMM folded in (W_x from L2 each step).
// Layer l's h -> seq_l[:,t] (full per-step buffering); layer1 gates x on layer0
// h-flags. Fixes over R7: conflict-free wave-per-row staging, LDS-aggregated
// coalesced publishes, rule-#18-safe pollers.
__global__ __launch_bounds__(512, 1)
void k_gru_fused(const bf16* __restrict__ W_ruh_T_all, const bf16* __restrict__ W_hh_T_all,
                 const bf16* __restrict__ W_x_T_all, const float* __restrict__ bias3,
                 const float* __restrict__ h0f, const bf16* __restrict__ h0b,
                 const bf16* __restrict__ x0, bf16* __restrict__ seq0,
                 bf16* __restrict__ seq1, bf16* __restrict__ rh_all,
                 unsigned* __restrict__ flags) {
  __shared__ char lds[57344];
  char* hp = lds;                       // h panel  [16][1024B] swizzled
  char* rp = lds + 16384;               // rh panel
  char* xp = lds + 32768;               // x panel
  float* ul = (float*)(lds + 49152);    // u exchange [16][64] f32
  char* rout = lds + 53248;             // [16][64] bf16 publish buffer
  char* hout = lds + 55296;             // [16][64] bf16 publish buffer

  const int tid = threadIdx.x;
  const int lane = tid & 63;
  const int wv = tid >> 6;
  const int cl = lane & 15, g = lane >> 4;
  const int l = blockIdx.x >> 5;
  const int wg5 = blockIdx.x & 31;
  const int mt = wg5 & 3, ng = wg5 >> 2;
  const bool is_u = (wv >= 4);
  const int wsub = wv & 3;
  const int nt = ng * 4 + wsub;                    // 0..31
  const int c = nt * 16 + cl;                      // 0..511
  const int colA = is_u ? 512 + c : c;

  unsigned* f_rh = flags + l * 256 + mt * 64;
  unsigned* f_h  = f_rh + 32;
  unsigned* f_h0 = flags + 0 * 256 + mt * 64 + 32;

  const bf16* Wr = W_ruh_T_all + (size_t)l * 1024 * 512;
  const bf16* Wh = W_hh_T_all + (size_t)l * 512 * 512;
  const bf16* Wx = W_x_T_all + (size_t)l * 1536 * 512;
  const bf16* xsrc = l ? seq0 : x0;
  bf16* seql = l ? seq1 : seq0;
  bf16* rh = rh_all + (size_t)l * 64 * 512;

  // register-resident recurrent weights (reused all 32 steps)
  bf16x8s bwA[16];
  { const bf16* pa = Wr + (size_t)colA * NH + g * 8;
#pragma unroll
    for (int k = 0; k < 16; k++) bwA[k] = *(const bf16x8s*)(pa + k * 32); }
  bf16x8s bwB[16];
  float h_reg[4];
  if (!is_u) {
    const bf16* pb = Wh + (size_t)c * NH + g * 8;
#pragma unroll
    for (int k = 0; k < 16; k++) bwB[k] = *(const bf16x8s*)(pb + k * 32);
#pragma unroll
    for (int j = 0; j < 4; j++)
      h_reg[j] = h0f[(size_t)(mt * 16 + g * 4 + j) * NH + c];
  }
  const bf16* wxA = Wx + (size_t)colA * NH + g * 8;
  const bf16* wxB = Wx + (size_t)(1024 + c) * NH + g * 8;
  const float bA = bias3[l * 1536 + colA];
  const float bB = bias3[l * 1536 + 1024 + c];

  // conflict-free staging: wave wv covers rows wv and wv+8; lane-contiguous 16B.
  const int in0 = lane * 16;
  const int dsw = in0 ^ ((wv & 7) << 4);           // (wv+8)&7 == wv&7
  auto stage = [&](char* dst, const char* srcbase, int rstr) {
    i32x4 v0 = ld16_sc(srcbase + (size_t)wv * rstr + in0);
    i32x4 v1 = ld16_sc(srcbase + (size_t)(wv + 8) * rstr + in0);
    wait_vm0();
    *(i32x4*)(dst + wv * 1024 + dsw) = v0;
    *(i32x4*)(dst + (wv + 8) * 1024 + dsw) = v1;
  };
  auto afrag = [&](const char* panel, int kk) {
    return *(const bf16x8s*)(panel + cl * 1024 + ((kk * 64 + g * 16) ^ ((cl & 7) << 4)));
  };
  auto poll8 = [&](const unsigned* f, unsigned tgt) {
    if (tid == 0) {
      for (;;) {
        i32x4 a = ld16_sc(f);
        i32x4 b = ld16_sc(f + 4);
        wait_vm0();                                  // #18: before the min chain
        if (min(min4u(a), min4u(b)) >= tgt) break;
        __builtin_amdgcn_s_sleep(2);
      }
    }
    __syncthreads();
    __builtin_amdgcn_sched_barrier(0);
  };

  for (int t = 0; t < NS; t++) {
    // ---- gate + stage phase-1 inputs
    if (t > 0) poll8(f_h, (unsigned)t);              // own h(t-1) complete
    if (l == 1) poll8(f_h0, (unsigned)(t + 1));      // x(t) = layer0 h(t)
    if (t == 0) stage(hp, (const char*)(h0b + (size_t)mt * 16 * NH), 1024);
    else        stage(hp, (const char*)seql + ((size_t)(mt * 16) * NS + (t - 1)) * 1024,
                      NS * 1024);
    stage(xp, (const char*)xsrc + ((size_t)(mt * 16) * NS + t) * 1024, NS * 1024);
    __syncthreads();
    // ---- phase 1: gate = sigmoid(x@Wx + h@W + bias)
    {
      f32x4 acc = {0.f, 0.f, 0.f, 0.f};
#pragma unroll
      for (int k4 = 0; k4 < 4; k4++) {
        bf16x8s w0 = *(const bf16x8s*)(wxA + (k4 * 4 + 0) * 32);
        bf16x8s w1 = *(const bf16x8s*)(wxA + (k4 * 4 + 1) * 32);
        bf16x8s w2 = *(const bf16x8s*)(wxA + (k4 * 4 + 2) * 32);
        bf16x8s w3 = *(const bf16x8s*)(wxA + (k4 * 4 + 3) * 32);
        acc = mfma16(afrag(hp, k4 * 4 + 0), bwA[k4 * 4 + 0], acc);
        acc = mfma16(afrag(hp, k4 * 4 + 1), bwA[k4 * 4 + 1], acc);
        acc = mfma16(afrag(hp, k4 * 4 + 2), bwA[k4 * 4 + 2], acc);
        acc = mfma16(afrag(hp, k4 * 4 + 3), bwA[k4 * 4 + 3], acc);
        acc = mfma16(afrag(xp, k4 * 4 + 0), w0, acc);
        acc = mfma16(afrag(xp, k4 * 4 + 1), w1, acc);
        acc = mfma16(afrag(xp, k4 * 4 + 2), w2, acc);
        acc = mfma16(afrag(xp, k4 * 4 + 3), w3, acc);
      }
#pragma unroll
      for (int j = 0; j < 4; j++) {
        float gate = 1.f / (1.f + expf(-(acc[j] + bA)));
        if (is_u) {
          ul[(g * 4 + j) * 64 + wsub * 16 + cl] = gate;
        } else {
          bf16 o = f2bf(gate * h_reg[j]);
          *(unsigned short*)(rout + (g * 4 + j) * 128 + (wsub * 16 + cl) * 2)
            = *(unsigned short*)&o;
        }
      }
    }
    __syncthreads();
    { // ---- publish rh (coalesced 16B sc-stores from rout)
      if (tid < 128) {
        int row = tid >> 3, ch = tid & 7;
        i32x4 v = *(i32x4*)(rout + row * 128 + ch * 16);
        st16_sc((char*)rh + (((size_t)(mt * 16 + row)) * NH + ng * 64 + ch * 8) * 2, v);
      }
      wait_vm0();
      __syncthreads();
      if (tid == 0) stud_sc(f_rh + ng, (unsigned)(t + 1));
    }
    poll8(f_rh, (unsigned)(t + 1));
    stage(rp, (const char*)(rh + (size_t)mt * 16 * NH), 1024);
    __syncthreads();
    // ---- phase 2: h_tilde + combine (r/h-waves)
    if (!is_u) {
      f32x4 acc = {0.f, 0.f, 0.f, 0.f};
#pragma unroll
      for (int k4 = 0; k4 < 4; k4++) {
        bf16x8s w0 = *(const bf16x8s*)(wxB + (k4 * 4 + 0) * 32);
        bf16x8s w1 = *(const bf16x8s*)(wxB + (k4 * 4 + 1) * 32);
        bf16x8s w2 = *(const bf16x8s*)(wxB + (k4 * 4 + 2) * 32);
        bf16x8s w3 = *(const bf16x8s*)(wxB + (k4 * 4 + 3) * 32);
        acc = mfma16(afrag(rp, k4 * 4 + 0), bwB[k4 * 4 + 0], acc);
        acc = mfma16(afrag(rp, k4 * 4 + 1), bwB[k4 * 4 + 1], acc);
        acc = mfma16(afrag(rp, k4 * 4 + 2), bwB[k4 * 4 + 2], acc);
        acc = mfma16(afrag(rp, k4 * 4 + 3), bwB[k4 * 4 + 3], acc);
        acc = mfma16(afrag(xp, k4 * 4 + 0), w0, acc);
        acc = mfma16(afrag(xp, k4 * 4 + 1), w1, acc);
        acc = mfma16(afrag(xp, k4 * 4 + 2), w2, acc);
        acc = mfma16(afrag(xp, k4 * 4 + 3), w3, acc);
      }
#pragma unroll
      for (int j = 0; j < 4; j++) {
        float htil = tanhf(acc[j] + bB);
        float u = ul[(g * 4 + j) * 64 + wsub * 16 + cl];
        float hnew = h_reg[j] * u + (1.f - u) * htil;
        h_reg[j] = hnew;
        bf16 hn = f2bf(hnew);
        *(unsigned short*)(hout + (g * 4 + j) * 128 + (wsub * 16 + cl) * 2)
          = *(unsigned short*)&hn;
      }
    }
    __syncthreads();
    { // ---- publish h into seq[l] (coalesced 16B sc-stores from hout)
      if (tid < 128) {
        int row = tid >> 3, ch = tid & 7;
        i32x4 v = *(i32x4*)(hout + row * 128 + ch * 16);
        st16_sc((char*)seql + (((size_t)(mt * 16 + row) * NS + t) * NH + ng * 64 + ch * 8) * 2, v);
      }
      wait_vm0();
      __syncthreads();
      if (tid == 0) stud_sc(f_h + ng, (unsigned)(t + 1));
    }
  }
}

// ---------------- logits = seq1 @ w_out + b_out, B-panel in LDS ----------------
// 256 thr/block; all 4 waves share one B panel (ng = bid>>3), mg = (bid&7)*4+wave.
__global__ __launch_bounds__(256, 2)
void k_gemm_out(const bf16* __restrict__ A, const bf16* __restrict__ BT,
                const float* __restrict__ bias, float* __restrict__ out) {
  __shared__ char bl[65536];                       // B panel [64][1024B] swizzled
  const int w = threadIdx.x >> 6;
  const int lane = threadIdx.x & 63;
  const int cl = lane & 15, g = lane >> 4;
  const int ng = blockIdx.x >> 3;                  // 0..156
  const int mg = (blockIdx.x & 7) * 4 + w;         // 0..31
  { // cooperative B-panel load: wave w rows w*16..+16 (rows < 10048, pad zeroed)
    const char* src = (const char*)(BT + (size_t)ng * 64 * NE) + (size_t)w * 16 * 1024;
#pragma unroll
    for (int rr = 0; rr < 16; rr++) {
      i32x4 v = *(const i32x4*)(src + rr * 1024 + lane * 16);
      *(i32x4*)(bl + (w * 16 + rr) * 1024 + ((lane * 16) ^ (((w * 16 + rr) & 7) << 4))) = v;
    }
  }
  __syncthreads();
  f32x4 acc[4][4] = {};
  const bf16* a0 = A + (size_t)(mg * 64 + cl) * NE + g * 8;
  bf16x8s av[2][4];
#pragma unroll
  for (int i = 0; i < 4; i++) av[0][i] = *(const bf16x8s*)(a0 + (size_t)(i * 16) * NE);
#pragma unroll
  for (int ks = 0; ks < 16; ks++) {
    const int cur = ks & 1;
    if (ks < 15) {
#pragma unroll
      for (int i = 0; i < 4; i++)
        av[cur ^ 1][i] = *(const bf16x8s*)(a0 + (size_t)(i * 16) * NE + (ks + 1) * 32);
    }
    bf16x8s bv[4];
#pragma unroll
    for (int i = 0; i < 4; i++)
      bv[i] = *(const bf16x8s*)(bl + (i * 16 + cl) * 1024 + ((ks * 64 + g * 16) ^ ((cl & 7) << 4)));
#pragma unroll
    for (int mi = 0; mi < 4; mi++)
#pragma unroll
      for (int ni = 0; ni < 4; ni++)
        acc[mi][ni] = mfma16(av[cur][mi], bv[ni], acc[mi][ni]);
  }
#pragma unroll
  for (int mi = 0; mi < 4; mi++) {
#pragma unroll
    for (int ni = 0; ni < 4; ni++) {
      int colb = ng * 64 + ni * 16 + cl;
      if (colb < NV) {
        float bv2 = bias[colb];
#pragma unroll
        for (int j = 0; j < 4; j++) {
          int row = mg * 64 + mi * 16 + g * 4 + j;
          out[(size_t)row * NV + colb] = acc[mi][ni][j] + bv2;
        }
      }
    }
  }
}

extern "C" void kernel_launch(void* const* d_in, const int* in_sizes, int n_in,
                              void* d_out, int out_size, void* d_ws, size_t ws_size,
                              hipStream_t stream) {
  const int*   tokens = (const int*)d_in[0];
  const float* cnn    = (const float*)d_in[1];
  const float* emb    = (const float*)d_in[2];
  const float* w_in   = (const float*)d_in[3];
  const float* b_in   = (const float*)d_in[4];
  const float* w_r    = (const float*)d_in[5];
  const float* b_r    = (const float*)d_in[6];
  const float* w_u    = (const float*)d_in[7];
  const float* b_u    = (const float*)d_in[8];
  const float* w_h    = (const float*)d_in[9];
  const float* b_h    = (const float*)d_in[10];
  const float* w_out  = (const float*)d_in[11];
  const float* b_out  = (const float*)d_in[12];
  float* out = (float*)d_out;

  char* ws = (char*)d_ws;
  size_t off = 0;
  auto alloc = [&](size_t bytes) { char* p = ws + off; off += (bytes + 255) & ~(size_t)255; return p; };
  bf16*  x0      = (bf16*) alloc((size_t)2048 * 512 * 2);
  bf16*  seq0    = (bf16*) alloc((size_t)2048 * 512 * 2);
  bf16*  seq1    = (bf16*) alloc((size_t)2048 * 512 * 2);
  float* h0f     = (float*)alloc((size_t)64 * 512 * 4);
  bf16*  h0b     = (bf16*) alloc((size_t)64 * 512 * 2);
  bf16*  rh_all  = (bf16*) alloc((size_t)2 * 64 * 512 * 2);
  float* bias3   = (float*)alloc((size_t)2 * 1536 * 4);
  bf16*  cnn_b   = (bf16*) alloc((size_t)64 * 2048 * 2);
  bf16*  w_in_T  = (bf16*) alloc((size_t)512 * 2048 * 2);
  bf16*  w_ruh_T = (bf16*) alloc((size_t)2 * 1024 * 512 * 2);
  bf16*  w_hh_T  = (bf16*) alloc((size_t)2 * 512 * 512 * 2);
  bf16*  w_x_T   = (bf16*) alloc((size_t)2 * 1536 * 512 * 2);
  bf16*  w_out_T = (bf16*) alloc((size_t)10048 * 512 * 2);
  unsigned* flags = (unsigned*)alloc(2048);   // [2][4][2][32] u32
  (void)ws_size; (void)in_sizes; (void)n_in; (void)out_size;

  hipMemsetAsync(flags, 0, 2048, stream);
  hipMemsetAsync(w_out_T + (size_t)10000 * 512, 0, (size_t)48 * 512 * 2, stream);

  k_embed<<<2048, 256, 0, stream>>>(tokens, emb, x0);
  k_cvt<<<512, 256, 0, stream>>>(cnn, cnn_b, 64 * 2048);
  k_transpose<<<dim3(16, 64), 256, 0, stream>>>(w_in, w_in_T, NF, NH);
  k_transpose12<<<dim3(16, 16, 12), 256, 0, stream>>>(w_r, w_u, w_h, w_ruh_T, w_hh_T, w_x_T);
  k_transpose<<<dim3(313, 16), 256, 0, stream>>>(w_out, w_out_T, 512, NV);
  k_bias3all<<<12, 256, 0, stream>>>(b_r, b_u, b_h, bias3);

  k_gemm_h0<<<32, 256, 0, stream>>>(cnn_b, w_in_T, b_in, h0f, h0b);

  k_gru_fused<<<64, 512, 0, stream>>>(w_ruh_T, w_hh_T, w_x_T, bias3, h0f, h0b,
                                      x0, seq0, seq1, rh_all, flags);

  k_gemm_out<<<1256, 256, 0, stream>>>(seq1, w_out_T, b_out, out);
}

// Round 12
// 303.988 us; speedup vs baseline: 2.4855x; 1.4570x over previous
//
#include <hip/hip_runtime.h>
#include <hip/hip_bf16.h>

typedef __hip_bfloat16 bf16;
typedef __attribute__((ext_vector_type(8))) short bf16x8s;
typedef __attribute__((ext_vector_type(4))) float f32x4;
typedef __attribute__((ext_vector_type(4))) int i32x4;

#define NB 64
#define NS 32
#define NV 10000
#define NE 512
#define NH 512
#define NF 2048
#define ND 1024

static __device__ __forceinline__ float bf2f(bf16 x) { return __bfloat162float(x); }
static __device__ __forceinline__ bf16 f2bf(float x) { return __float2bfloat16(x); }
static __device__ __forceinline__ f32x4 mfma16(bf16x8s a, bf16x8s b, f32x4 c) {
  return __builtin_amdgcn_mfma_f32_16x16x32_bf16(a, b, c, 0, 0, 0);
}

// ---- LLC-coherent (cross-XCD) accesses, bypassing per-XCD L1/L2 via sc0 sc1.
// Compiler does NOT track vmcnt — MUST wait_vm0() (waitcnt + sched_barrier,
// rule #18) before ANY use of results, including register-only VALU use.
static __device__ __forceinline__ i32x4 ld16_sc(const void* p) {
  i32x4 r;
  asm volatile("global_load_dwordx4 %0, %1, off sc0 sc1" : "=v"(r) : "v"(p) : "memory");
  return r;
}
static __device__ __forceinline__ void st16_sc(void* p, i32x4 v) {
  asm volatile("global_store_dwordx4 %0, %1, off sc0 sc1" :: "v"(p), "v"(v) : "memory");
}
static __device__ __forceinline__ void stud_sc(void* p, unsigned v) {
  asm volatile("global_store_dword %0, %1, off sc0 sc1" :: "v"(p), "v"(v) : "memory");
}
static __device__ __forceinline__ void wait_vm0() {
  asm volatile("s_waitcnt vmcnt(0)" ::: "memory");
  __builtin_amdgcn_sched_barrier(0);
}
static __device__ __forceinline__ unsigned min4u(i32x4 a) {
  return min(min((unsigned)a[0], (unsigned)a[1]), min((unsigned)a[2], (unsigned)a[3]));
}

// One 16x16 output tile per wave (cached path, plain GEMMs).
__device__ __forceinline__ f32x4 wave_tile16(const bf16* A, const bf16* BT,
                                             int lda, int K, int m0, int n0) {
  int lane = threadIdx.x & 63;
  int r = lane & 15, g = lane >> 4;
  const bf16* ap = A + (size_t)(m0 + r) * lda + g * 8;
  const bf16* bp = BT + (size_t)(n0 + r) * K + g * 8;
  f32x4 acc = {0.f, 0.f, 0.f, 0.f};
#pragma unroll 4
  for (int k = 0; k < K; k += 32) {
    bf16x8s a = *(const bf16x8s*)(ap + k);
    bf16x8s b = *(const bf16x8s*)(bp + k);
    acc = mfma16(a, b, acc);
  }
  return acc;
}

// ---------------- embedding gather + f32->bf16 ([b*S+t][512]) ----------------
__global__ void k_embed(const int* __restrict__ tokens, const float* __restrict__ emb,
                        bf16* __restrict__ x0) {
  int row = blockIdx.x;
  int tok = tokens[row];
  const float2* src = (const float2*)(emb + (size_t)tok * NE);
  uint32_t* dst = (uint32_t*)(x0 + (size_t)row * NE);
  float2 v = src[threadIdx.x];
  __hip_bfloat162 p;
  p.x = f2bf(v.x); p.y = f2bf(v.y);
  dst[threadIdx.x] = *(uint32_t*)&p;
}

__global__ void k_cvt(const float* __restrict__ src, bf16* __restrict__ dst, int n) {
  int i = blockIdx.x * 256 + threadIdx.x;
  if (i < n) dst[i] = f2bf(src[i]);
}

__global__ void k_transpose(const float* __restrict__ src, bf16* __restrict__ dst,
                            int K, int N) {
  __shared__ float tile[32][33];
  int n0 = blockIdx.x * 32, k0 = blockIdx.y * 32;
  int tx = threadIdx.x & 31, ty = threadIdx.x >> 5;
  for (int i = ty; i < 32; i += 8) {
    int k = k0 + i, n = n0 + tx;
    tile[i][tx] = (k < K && n < N) ? src[(size_t)k * N + n] : 0.f;
  }
  __syncthreads();
  for (int i = ty; i < 32; i += 8) {
    int n = n0 + i, k = k0 + tx;
    if (n < N && k < K) dst[(size_t)n * K + k] = f2bf(tile[tx][i]);
  }
}

__global__ void k_transpose12(const float* __restrict__ w_r, const float* __restrict__ w_u,
                              const float* __restrict__ w_h, bf16* __restrict__ ruhT,
                              bf16* __restrict__ hhT, bf16* __restrict__ xT) {
  int z = blockIdx.z, l = z / 6, q = z % 6;
  const float* srcs[6] = {
    w_r + (size_t)l * ND * NH + (size_t)512 * NH,
    w_u + (size_t)l * ND * NH + (size_t)512 * NH,
    w_h + (size_t)l * ND * NH + (size_t)512 * NH,
    w_r + (size_t)l * ND * NH,
    w_u + (size_t)l * ND * NH,
    w_h + (size_t)l * ND * NH };
  bf16* dsts[6] = {
    ruhT + (size_t)l * 1024 * 512,
    ruhT + (size_t)l * 1024 * 512 + 512 * 512,
    hhT  + (size_t)l * 512 * 512,
    xT   + (size_t)l * 1536 * 512,
    xT   + (size_t)l * 1536 * 512 + 512 * 512,
    xT   + (size_t)l * 1536 * 512 + 1024 * 512 };
  const float* src = srcs[q];
  bf16* dst = dsts[q];
  __shared__ float tile[32][33];
  int n0 = blockIdx.x * 32, k0 = blockIdx.y * 32;
  int tx = threadIdx.x & 31, ty = threadIdx.x >> 5;
  for (int i = ty; i < 32; i += 8)
    tile[i][tx] = src[(size_t)(k0 + i) * NH + n0 + tx];
  __syncthreads();
  for (int i = ty; i < 32; i += 8)
    dst[(size_t)(n0 + i) * NH + k0 + tx] = f2bf(tile[tx][i]);
}

__global__ void k_bias3all(const float* __restrict__ br, const float* __restrict__ bu,
                           const float* __restrict__ bh, float* __restrict__ bias) {
  int i = blockIdx.x * 256 + threadIdx.x;
  if (i < 3072) {
    int l = i / 1536, c = i % 1536;
    const float* s = (c < 512) ? (br + l * 512 + c)
                   : (c < 1024 ? (bu + l * 512 + (c - 512)) : (bh + l * 512 + (c - 1024)));
    bias[i] = *s;
  }
}

// ---------------- h0 = cnn @ w_in + b_in, dual-store f32 + bf16 ----------------
__global__ void k_gemm_h0(const bf16* __restrict__ A, const bf16* __restrict__ BT,
                          const float* __restrict__ bias,
                          float* __restrict__ h0f, bf16* __restrict__ h0b) {
  int wid = blockIdx.x * 4 + (threadIdx.x >> 6);
  int mt = wid & 3, nt = wid >> 2;
  f32x4 acc = wave_tile16(A, BT, NF, NF, mt * 16, nt * 16);
  int lane = threadIdx.x & 63;
  int cl = lane & 15, g = lane >> 4;
  int col = nt * 16 + cl;
  float bv = bias[col];
#pragma unroll
  for (int j = 0; j < 4; j++) {
    int row = mt * 16 + g * 4 + j;
    float v = acc[j] + bv;
    h0f[(size_t)row * NH + col] = v;
    h0b[(size_t)row * NH + col] = f2bf(v);
  }
}

// ---------------- fused persistent 2-layer GRU + x-part workers ----------------
// 160 WGs x 512 thr, 1 WG/CU. WGs 0..63: recurrence (R11 structure: l=bid>>5,
// mt=bid&3, ng=(bid&31)>>2) with the x-GEMM REMOVED — pre arrives via a 4-slot
// ring in TRANSPOSED [slot][c][b] f32 layout (one 16B sc-load per thread).
// WGs 64..159: x-part workers (l, group gg, col-slice cw 0..11, 128 cols each)
// computing pre_l(t)=x_l(t)@Wx+b; layer1's x = seq0 (gated on layer0 h-flags).
// Flags: f_h[(l*4+mt)*32+ng], f_rh[256+...], f_pre[512+(l*4+mt)*32+cw].
__global__ __launch_bounds__(512, 1)
void k_gru2(const bf16* __restrict__ w_ruh, const bf16* __restrict__ w_hh,
            const bf16* __restrict__ w_x, const float* __restrict__ bias3,
            const float* __restrict__ h0f, const bf16* __restrict__ h0b,
            const bf16* __restrict__ x0, bf16* __restrict__ seq0,
            bf16* __restrict__ seq1, bf16* __restrict__ rh_all,
            float* __restrict__ pre, unsigned* __restrict__ flags) {
  __shared__ char lds[40960];
  const int tid = threadIdx.x;
  const int lane = tid & 63;
  const int wv = tid >> 6;
  const int cl = lane & 15, g4 = lane >> 4;
  const int bid = blockIdx.x;
  const int in0 = lane * 16;
  const int dsw = in0 ^ ((wv & 7) << 4);

  // stage a 16x512 bf16 slab -> swizzled LDS panel (wave-per-row, conflict-free)
  auto stage = [&](char* dst, const char* srcbase, int rstr) {
    i32x4 v0 = ld16_sc(srcbase + (size_t)wv * rstr + in0);
    i32x4 v1 = ld16_sc(srcbase + (size_t)(wv + 8) * rstr + in0);
    wait_vm0();
    *(i32x4*)(dst + wv * 1024 + dsw) = v0;
    *(i32x4*)(dst + (wv + 8) * 1024 + dsw) = v1;
  };
  auto afrag = [&](const char* panel, int kk) {
    return *(const bf16x8s*)(panel + cl * 1024 + ((kk * 64 + g4 * 16) ^ ((cl & 7) << 4)));
  };
  auto poll8 = [&](const unsigned* f, unsigned tgt) {
    if (tid == 0) {
      for (;;) {
        i32x4 a = ld16_sc(f);
        i32x4 b = ld16_sc(f + 4);
        wait_vm0();                                  // #18 before the min chain
        if (min(min4u(a), min4u(b)) >= tgt) break;
        __builtin_amdgcn_s_sleep(1);
      }
    }
    __syncthreads();
    __builtin_amdgcn_sched_barrier(0);
  };

  if (bid < 64) {
    // ================= recurrence =================
    const int l = bid >> 5, wg5 = bid & 31, mt = wg5 & 3, ng = wg5 >> 2;
    const bool is_u = (wv >= 4);
    const int wsub = wv & 3;
    const int c = (ng * 4 + wsub) * 16 + cl;         // own col 0..511
    const int colA = is_u ? 512 + c : c;
    char* hp = lds;                                  // h panel [16][1024B] swizzled
    char* rp = lds + 16384;                          // rh panel
    float* ul = (float*)(lds + 32768);               // u exchange [16][64] f32
    char* rout = lds + 36864;                        // [16][64] bf16 publish buf
    char* hout = lds + 38912;                        // [16][64] bf16 publish buf

    unsigned* f_h  = flags + (l * 4 + mt) * 32;
    unsigned* f_rh = flags + 256 + (l * 4 + mt) * 32;
    unsigned* f_pre = flags + 512 + (l * 4 + mt) * 32;

    bf16* seql = l ? seq1 : seq0;
    bf16* rh = rh_all + (size_t)l * 64 * 512;
    float* prel = pre + (size_t)l * 4 * 1536 * 64;

    // register-resident recurrent weights (reused all 32 steps)
    bf16x8s bwA[16];
    { const bf16* pa = w_ruh + (size_t)l * 1024 * 512 + (size_t)colA * NH + g4 * 8;
#pragma unroll
      for (int k = 0; k < 16; k++) bwA[k] = *(const bf16x8s*)(pa + k * 32); }
    bf16x8s bwB[16];
    float h_reg[4];
    if (!is_u) {
      const bf16* pb = w_hh + (size_t)l * 512 * 512 + (size_t)c * NH + g4 * 8;
#pragma unroll
      for (int k = 0; k < 16; k++) bwB[k] = *(const bf16x8s*)(pb + k * 32);
#pragma unroll
      for (int j = 0; j < 4; j++)
        h_reg[j] = h0f[(size_t)(mt * 16 + g4 * 4 + j) * NH + c];
    }

    for (int t = 0; t < NS; t++) {
      // ---- combined poll: pre(t) ready AND (t>0) own h(t-1) complete
      if (tid == 0) {
        for (;;) {
          i32x4 p0 = ld16_sc(f_pre), p1 = ld16_sc(f_pre + 4), p2 = ld16_sc(f_pre + 8);
          i32x4 h0_, h1_;
          if (t) { h0_ = ld16_sc(f_h); h1_ = ld16_sc(f_h + 4); }
          wait_vm0();                                // #18
          unsigned mnp = min(min(min4u(p0), min4u(p1)), min4u(p2));
          bool ok = mnp >= (unsigned)(t + 1);
          if (t) ok = ok && (min(min4u(h0_), min4u(h1_)) >= (unsigned)t);
          if (ok) break;
          __builtin_amdgcn_s_sleep(1);
        }
      }
      __syncthreads();
      __builtin_amdgcn_sched_barrier(0);
      // ---- issue pre vec-loads + h-stage (single drain inside stage)
      const int slot = t & 3;
      i32x4 pv1 = ld16_sc(prel + ((size_t)(slot * 1536 + colA) * 64 + mt * 16 + g4 * 4));
      i32x4 pv2 = {0, 0, 0, 0};
      if (!is_u)
        pv2 = ld16_sc(prel + ((size_t)(slot * 1536 + 1024 + c) * 64 + mt * 16 + g4 * 4));
      if (t == 0) stage(hp, (const char*)(h0b + (size_t)mt * 16 * NH), 1024);
      else        stage(hp, (const char*)seql + ((size_t)(mt * 16) * NS + (t - 1)) * 1024,
                        NS * 1024);
      __syncthreads();
      f32x4 pA = *(f32x4*)&pv1;
      f32x4 pB = *(f32x4*)&pv2;
      // ---- phase 1: gate = sigmoid(h@W + pre)
      {
        f32x4 acc = {0.f, 0.f, 0.f, 0.f};
#pragma unroll
        for (int kk = 0; kk < 16; kk++) acc = mfma16(afrag(hp, kk), bwA[kk], acc);
#pragma unroll
        for (int j = 0; j < 4; j++) {
          float gate = 1.f / (1.f + expf(-(acc[j] + pA[j])));
          if (is_u) {
            ul[(g4 * 4 + j) * 64 + wsub * 16 + cl] = gate;
          } else {
            bf16 o = f2bf(gate * h_reg[j]);
            *(unsigned short*)(rout + (g4 * 4 + j) * 128 + (wsub * 16 + cl) * 2)
              = *(unsigned short*)&o;
          }
        }
      }
      __syncthreads();
      { // ---- publish rh (coalesced 16B sc-stores)
        if (tid < 128) {
          int row = tid >> 3, ch = tid & 7;
          i32x4 v = *(i32x4*)(rout + row * 128 + ch * 16);
          st16_sc((char*)rh + (((size_t)(mt * 16 + row)) * NH + ng * 64 + ch * 8) * 2, v);
        }
        wait_vm0();
        __syncthreads();
        if (tid == 0) stud_sc(f_rh + ng, (unsigned)(t + 1));
      }
      poll8(f_rh, (unsigned)(t + 1));
      stage(rp, (const char*)(rh + (size_t)mt * 16 * NH), 1024);
      __syncthreads();
      // ---- phase 2: h_tilde + combine (r/h-waves)
      if (!is_u) {
        f32x4 acc = {0.f, 0.f, 0.f, 0.f};
#pragma unroll
        for (int kk = 0; kk < 16; kk++) acc = mfma16(afrag(rp, kk), bwB[kk], acc);
#pragma unroll
        for (int j = 0; j < 4; j++) {
          float htil = tanhf(acc[j] + pB[j]);
          float u = ul[(g4 * 4 + j) * 64 + wsub * 16 + cl];
          float hnew = h_reg[j] * u + (1.f - u) * htil;
          h_reg[j] = hnew;
          bf16 hn = f2bf(hnew);
          *(unsigned short*)(hout + (g4 * 4 + j) * 128 + (wsub * 16 + cl) * 2)
            = *(unsigned short*)&hn;
        }
      }
      __syncthreads();
      { // ---- publish h into seq[l] ([b][t][512], coalesced 16B)
        if (tid < 128) {
          int row = tid >> 3, ch = tid & 7;
          i32x4 v = *(i32x4*)(hout + row * 128 + ch * 16);
          st16_sc((char*)seql + (((size_t)(mt * 16 + row) * NS + t) * NH + ng * 64 + ch * 8) * 2, v);
        }
        wait_vm0();
        __syncthreads();
        if (tid == 0) stud_sc(f_h + ng, (unsigned)(t + 1));
      }
    }
  } else {
    // ================= x-part worker =================
    const int wb = bid - 64;                         // 0..95
    const int l = wb / 48, w48 = wb % 48, gg = w48 & 3, cw = w48 >> 2;  // cw 0..11
    char* xpan = lds;
    const int col = cw * 128 + wv * 16 + cl;         // own output col 0..1535
    const bf16* xsrc = l ? seq0 : x0;
    float* prel = pre + (size_t)l * 4 * 1536 * 64;
    unsigned* f_h0g = flags + (0 * 4 + gg) * 32;     // layer0 h flags (x gating)
    unsigned* f_own = flags + (l * 4 + gg) * 32;     // own-layer h flags (ring gate)
    unsigned* f_out = flags + 512 + (l * 4 + gg) * 32 + cw;

    bf16x8s wxw[16];
    { const bf16* pw = w_x + (size_t)l * 1536 * 512 + (size_t)col * 512 + g4 * 8;
#pragma unroll
      for (int kk = 0; kk < 16; kk++) wxw[kk] = *(const bf16x8s*)(pw + kk * 32); }
    const float bz = bias3[l * 1536 + col];

    for (int t = 0; t < NS; t++) {
      // ---- combined poll: (l==1) seq0(t) ready; (t>=4) ring-overwrite gate
      if (l == 1 || t >= 4) {
        if (tid == 0) {
          for (;;) {
            i32x4 a0 = {0,0,0,0}, a1 = {0,0,0,0}, b0 = {0,0,0,0}, b1 = {0,0,0,0};
            if (l == 1) { a0 = ld16_sc(f_h0g); a1 = ld16_sc(f_h0g + 4); }
            if (t >= 4) { b0 = ld16_sc(f_own); b1 = ld16_sc(f_own + 4); }
            wait_vm0();                              // #18
            bool ok = true;
            if (l == 1) ok = min(min4u(a0), min4u(a1)) >= (unsigned)(t + 1);
            if (t >= 4) ok = ok && (min(min4u(b0), min4u(b1)) >= (unsigned)(t - 3));
            if (ok) break;
            __builtin_amdgcn_s_sleep(1);
          }
        }
        __syncthreads();
        __builtin_amdgcn_sched_barrier(0);
      }
      // ---- stage x slab (group gg rows, time t; [b][t][512] layout)
      stage(xpan, (const char*)xsrc + ((size_t)(gg * 16) * NS + t) * 1024, NS * 1024);
      __syncthreads();
      // ---- 16 MFMA: pre = x@Wx
      f32x4 acc = {0.f, 0.f, 0.f, 0.f};
#pragma unroll
      for (int kk = 0; kk < 16; kk++) acc = mfma16(afrag(xpan, kk), wxw[kk], acc);
      // ---- store transposed [slot][col][b]: one 16B sc-store per lane
      {
        f32x4 o;
#pragma unroll
        for (int j = 0; j < 4; j++) o[j] = acc[j] + bz;
        st16_sc(prel + ((size_t)((t & 3) * 1536 + col) * 64 + gg * 16 + g4 * 4),
                *(i32x4*)&o);
      }
      wait_vm0();
      __syncthreads();
      if (tid == 0) stud_sc(f_out, (unsigned)(t + 1));
    }
  }
}

// ---------------- logits = seq1 @ w_out + b_out, B-panel in LDS ----------------
__global__ __launch_bounds__(256, 2)
void k_gemm_out(const bf16* __restrict__ A, const bf16* __restrict__ BT,
                const float* __restrict__ bias, float* __restrict__ out) {
  __shared__ char bl[65536];                       // B panel [64][1024B] swizzled
  const int w = threadIdx.x >> 6;
  const int lane = threadIdx.x & 63;
  const int cl = lane & 15, g = lane >> 4;
  const int ng = blockIdx.x >> 3;                  // 0..156
  const int mg = (blockIdx.x & 7) * 4 + w;         // 0..31
  {
    const char* src = (const char*)(BT + (size_t)ng * 64 * NE) + (size_t)w * 16 * 1024;
#pragma unroll
    for (int rr = 0; rr < 16; rr++) {
      i32x4 v = *(const i32x4*)(src + rr * 1024 + lane * 16);
      *(i32x4*)(bl + (w * 16 + rr) * 1024 + ((lane * 16) ^ (((w * 16 + rr) & 7) << 4))) = v;
    }
  }
  __syncthreads();
  f32x4 acc[4][4] = {};
  const bf16* a0 = A + (size_t)(mg * 64 + cl) * NE + g * 8;
  bf16x8s av[2][4];
#pragma unroll
  for (int i = 0; i < 4; i++) av[0][i] = *(const bf16x8s*)(a0 + (size_t)(i * 16) * NE);
#pragma unroll
  for (int ks = 0; ks < 16; ks++) {
    const int cur = ks & 1;
    if (ks < 15) {
#pragma unroll
      for (int i = 0; i < 4; i++)
        av[cur ^ 1][i] = *(const bf16x8s*)(a0 + (size_t)(i * 16) * NE + (ks + 1) * 32);
    }
    bf16x8s bv[4];
#pragma unroll
    for (int i = 0; i < 4; i++)
      bv[i] = *(const bf16x8s*)(bl + (i * 16 + cl) * 1024 + ((ks * 64 + g * 16) ^ ((cl & 7) << 4)));
#pragma unroll
    for (int mi = 0; mi < 4; mi++)
#pragma unroll
      for (int ni = 0; ni < 4; ni++)
        acc[mi][ni] = mfma16(av[cur][mi], bv[ni], acc[mi][ni]);
  }
#pragma unroll
  for (int mi = 0; mi < 4; mi++) {
#pragma unroll
    for (int ni = 0; ni < 4; ni++) {
      int colb = ng * 64 + ni * 16 + cl;
      if (colb < NV) {
        float bv2 = bias[colb];
#pragma unroll
        for (int j = 0; j < 4; j++) {
          int row = mg * 64 + mi * 16 + g * 4 + j;
          out[(size_t)row * NV + colb] = acc[mi][ni][j] + bv2;
        }
      }
    }
  }
}

extern "C" void kernel_launch(void* const* d_in, const int* in_sizes, int n_in,
                              void* d_out, int out_size, void* d_ws, size_t ws_size,
                              hipStream_t stream) {
  const int*   tokens = (const int*)d_in[0];
  const float* cnn    = (const float*)d_in[1];
  const float* emb    = (const float*)d_in[2];
  const float* w_in   = (const float*)d_in[3];
  const float* b_in   = (const float*)d_in[4];
  const float* w_r    = (const float*)d_in[5];
  const float* b_r    = (const float*)d_in[6];
  const float* w_u    = (const float*)d_in[7];
  const float* b_u    = (const float*)d_in[8];
  const float* w_h    = (const float*)d_in[9];
  const float* b_h    = (const float*)d_in[10];
  const float* w_out  = (const float*)d_in[11];
  const float* b_out  = (const float*)d_in[12];
  float* out = (float*)d_out;

  char* ws = (char*)d_ws;
  size_t off = 0;
  auto alloc = [&](size_t bytes) { char* p = ws + off; off += (bytes + 255) & ~(size_t)255; return p; };
  bf16*  x0      = (bf16*) alloc((size_t)2048 * 512 * 2);
  bf16*  seq0    = (bf16*) alloc((size_t)2048 * 512 * 2);
  bf16*  seq1    = (bf16*) alloc((size_t)2048 * 512 * 2);
  float* pre     = (float*)alloc((size_t)2 * 4 * 1536 * 64 * 4);   // [l][ring4][c][b]
  float* h0f     = (float*)alloc((size_t)64 * 512 * 4);
  bf16*  h0b     = (bf16*) alloc((size_t)64 * 512 * 2);
  bf16*  rh_all  = (bf16*) alloc((size_t)2 * 64 * 512 * 2);
  float* bias3   = (float*)alloc((size_t)2 * 1536 * 4);
  bf16*  cnn_b   = (bf16*) alloc((size_t)64 * 2048 * 2);
  bf16*  w_in_T  = (bf16*) alloc((size_t)512 * 2048 * 2);
  bf16*  w_ruh_T = (bf16*) alloc((size_t)2 * 1024 * 512 * 2);
  bf16*  w_hh_T  = (bf16*) alloc((size_t)2 * 512 * 512 * 2);
  bf16*  w_x_T   = (bf16*) alloc((size_t)2 * 1536 * 512 * 2);
  bf16*  w_out_T = (bf16*) alloc((size_t)10048 * 512 * 2);
  unsigned* flags = (unsigned*)alloc(4096);   // 1024 dwords: f_h/f_rh/f_pre
  (void)ws_size; (void)in_sizes; (void)n_in; (void)out_size;

  hipMemsetAsync(flags, 0, 4096, stream);
  hipMemsetAsync(w_out_T + (size_t)10000 * 512, 0, (size_t)48 * 512 * 2, stream);

  k_embed<<<2048, 256, 0, stream>>>(tokens, emb, x0);
  k_cvt<<<512, 256, 0, stream>>>(cnn, cnn_b, 64 * 2048);
  k_transpose<<<dim3(16, 64), 256, 0, stream>>>(w_in, w_in_T, NF, NH);
  k_transpose12<<<dim3(16, 16, 12), 256, 0, stream>>>(w_r, w_u, w_h, w_ruh_T, w_hh_T, w_x_T);
  k_transpose<<<dim3(313, 16), 256, 0, stream>>>(w_out, w_out_T, 512, NV);
  k_bias3all<<<12, 256, 0, stream>>>(b_r, b_u, b_h, bias3);

  k_gemm_h0<<<32, 256, 0, stream>>>(cnn_b, w_in_T, b_in, h0f, h0b);

  k_gru2<<<160, 512, 0, stream>>>(w_ruh_T, w_hh_T, w_x_T, bias3, h0f, h0b,
                                  x0, seq0, seq1, rh_all, pre, flags);

  k_gemm_out<<<1256, 256, 0, stream>>>(seq1, w_out_T, b_out, out);
}

// Round 13
// 260.760 us; speedup vs baseline: 2.8975x; 1.1658x over previous
//
#include <hip/hip_runtime.h>
#include <hip/hip_bf16.h>

typedef __hip_bfloat16 bf16;
typedef __attribute__((ext_vector_type(8))) short bf16x8s;
typedef __attribute__((ext_vector_type(4))) float f32x4;
typedef __attribute__((ext_vector_type(4))) int i32x4;

#define NB 64
#define NS 32
#define NV 10000
#define NE 512
#define NH 512
#define NF 2048
#define ND 1024

static __device__ __forceinline__ float bf2f(bf16 x) { return __bfloat162float(x); }
static __device__ __forceinline__ bf16 f2bf(float x) { return __float2bfloat16(x); }
static __device__ __forceinline__ f32x4 mfma16(bf16x8s a, bf16x8s b, f32x4 c) {
  return __builtin_amdgcn_mfma_f32_16x16x32_bf16(a, b, c, 0, 0, 0);
}

// ---- LLC-coherent (cross-XCD) accesses, bypassing per-XCD L1/L2 via sc0 sc1.
// Compiler does NOT track vmcnt — MUST wait_vm0() (waitcnt + sched_barrier,
// rule #18) before ANY use of results, including register-only VALU use.
static __device__ __forceinline__ i32x4 ld16_sc(const void* p) {
  i32x4 r;
  asm volatile("global_load_dwordx4 %0, %1, off sc0 sc1" : "=v"(r) : "v"(p) : "memory");
  return r;
}
static __device__ __forceinline__ void st16_sc(void* p, i32x4 v) {
  asm volatile("global_store_dwordx4 %0, %1, off sc0 sc1" :: "v"(p), "v"(v) : "memory");
}
static __device__ __forceinline__ void stud_sc(void* p, unsigned v) {
  asm volatile("global_store_dword %0, %1, off sc0 sc1" :: "v"(p), "v"(v) : "memory");
}
static __device__ __forceinline__ void wait_vm0() {
  asm volatile("s_waitcnt vmcnt(0)" ::: "memory");
  __builtin_amdgcn_sched_barrier(0);
}
static __device__ __forceinline__ unsigned min4u(i32x4 a) {
  return min(min((unsigned)a[0], (unsigned)a[1]), min((unsigned)a[2], (unsigned)a[3]));
}

// One 16x16 output tile per wave (cached path, plain GEMMs).
__device__ __forceinline__ f32x4 wave_tile16(const bf16* A, const bf16* BT,
                                             int lda, int K, int m0, int n0) {
  int lane = threadIdx.x & 63;
  int r = lane & 15, g = lane >> 4;
  const bf16* ap = A + (size_t)(m0 + r) * lda + g * 8;
  const bf16* bp = BT + (size_t)(n0 + r) * K + g * 8;
  f32x4 acc = {0.f, 0.f, 0.f, 0.f};
#pragma unroll 4
  for (int k = 0; k < K; k += 32) {
    bf16x8s a = *(const bf16x8s*)(ap + k);
    bf16x8s b = *(const bf16x8s*)(bp + k);
    acc = mfma16(a, b, acc);
  }
  return acc;
}

// ---------------- embedding gather + f32->bf16 ([b*S+t][512]) ----------------
__global__ void k_embed(const int* __restrict__ tokens, const float* __restrict__ emb,
                        bf16* __restrict__ x0) {
  int row = blockIdx.x;
  int tok = tokens[row];
  const float2* src = (const float2*)(emb + (size_t)tok * NE);
  uint32_t* dst = (uint32_t*)(x0 + (size_t)row * NE);
  float2 v = src[threadIdx.x];
  __hip_bfloat162 p;
  p.x = f2bf(v.x); p.y = f2bf(v.y);
  dst[threadIdx.x] = *(uint32_t*)&p;
}

__global__ void k_cvt(const float* __restrict__ src, bf16* __restrict__ dst, int n) {
  int i = blockIdx.x * 256 + threadIdx.x;
  if (i < n) dst[i] = f2bf(src[i]);
}

__global__ void k_transpose(const float* __restrict__ src, bf16* __restrict__ dst,
                            int K, int N) {
  __shared__ float tile[32][33];
  int n0 = blockIdx.x * 32, k0 = blockIdx.y * 32;
  int tx = threadIdx.x & 31, ty = threadIdx.x >> 5;
  for (int i = ty; i < 32; i += 8) {
    int k = k0 + i, n = n0 + tx;
    tile[i][tx] = (k < K && n < N) ? src[(size_t)k * N + n] : 0.f;
  }
  __syncthreads();
  for (int i = ty; i < 32; i += 8) {
    int n = n0 + i, k = k0 + tx;
    if (n < N && k < K) dst[(size_t)n * K + k] = f2bf(tile[tx][i]);
  }
}

__global__ void k_transpose12(const float* __restrict__ w_r, const float* __restrict__ w_u,
                              const float* __restrict__ w_h, bf16* __restrict__ ruhT,
                              bf16* __restrict__ hhT, bf16* __restrict__ xT) {
  int z = blockIdx.z, l = z / 6, q = z % 6;
  const float* srcs[6] = {
    w_r + (size_t)l * ND * NH + (size_t)512 * NH,
    w_u + (size_t)l * ND * NH + (size_t)512 * NH,
    w_h + (size_t)l * ND * NH + (size_t)512 * NH,
    w_r + (size_t)l * ND * NH,
    w_u + (size_t)l * ND * NH,
    w_h + (size_t)l * ND * NH };
  bf16* dsts[6] = {
    ruhT + (size_t)l * 1024 * 512,
    ruhT + (size_t)l * 1024 * 512 + 512 * 512,
    hhT  + (size_t)l * 512 * 512,
    xT   + (size_t)l * 1536 * 512,
    xT   + (size_t)l * 1536 * 512 + 512 * 512,
    xT   + (size_t)l * 1536 * 512 + 1024 * 512 };
  const float* src = srcs[q];
  bf16* dst = dsts[q];
  __shared__ float tile[32][33];
  int n0 = blockIdx.x * 32, k0 = blockIdx.y * 32;
  int tx = threadIdx.x & 31, ty = threadIdx.x >> 5;
  for (int i = ty; i < 32; i += 8)
    tile[i][tx] = src[(size_t)(k0 + i) * NH + n0 + tx];
  __syncthreads();
  for (int i = ty; i < 32; i += 8)
    dst[(size_t)(n0 + i) * NH + k0 + tx] = f2bf(tile[tx][i]);
}

__global__ void k_bias3all(const float* __restrict__ br, const float* __restrict__ bu,
                           const float* __restrict__ bh, float* __restrict__ bias) {
  int i = blockIdx.x * 256 + threadIdx.x;
  if (i < 3072) {
    int l = i / 1536, c = i % 1536;
    const float* s = (c < 512) ? (br + l * 512 + c)
                   : (c < 1024 ? (bu + l * 512 + (c - 512)) : (bh + l * 512 + (c - 1024)));
    bias[i] = *s;
  }
}

// ---------------- h0 = cnn @ w_in + b_in, dual-store f32 + bf16 ----------------
__global__ void k_gemm_h0(const bf16* __restrict__ A, const bf16* __restrict__ BT,
                          const float* __restrict__ bias,
                          float* __restrict__ h0f, bf16* __restrict__ h0b) {
  int wid = blockIdx.x * 4 + (threadIdx.x >> 6);
  int mt = wid & 3, nt = wid >> 2;
  f32x4 acc = wave_tile16(A, BT, NF, NF, mt * 16, nt * 16);
  int lane = threadIdx.x & 63;
  int cl = lane & 15, g = lane >> 4;
  int col = nt * 16 + cl;
  float bv = bias[col];
#pragma unroll
  for (int j = 0; j < 4; j++) {
    int row = mt * 16 + g * 4 + j;
    float v = acc[j] + bv;
    h0f[(size_t)row * NH + col] = v;
    h0b[(size_t)row * NH + col] = f2bf(v);
  }
}

// ---------------- fused persistent: 2-layer GRU + x-workers + OUT-workers ----------------
// 256 WGs x 512 thr, exactly 1 WG/CU. WGs 0..63: recurrence (R12 structure).
// WGs 64..159: x-part workers filling the 4-slot transposed pre ring.
// WGs 160..255: output-GEMM workers — stream logits as layer-1 steps complete:
//   worker j owns 8 col-tiles (j*8+wv)*16; B-fragments register-resident; per t:
//   poll compact l1-h flags (32 dwords @ flags+960), stage seq1 t-slab (64KB) via
//   sc-loads into swizzled LDS, 64 MFMA/wave, store out rows. Pure consumers.
__global__ __launch_bounds__(512, 1)
void k_gru2(const bf16* __restrict__ w_ruh, const bf16* __restrict__ w_hh,
            const bf16* __restrict__ w_x, const float* __restrict__ bias3,
            const float* __restrict__ h0f, const bf16* __restrict__ h0b,
            const bf16* __restrict__ x0, bf16* __restrict__ seq0,
            bf16* __restrict__ seq1, bf16* __restrict__ rh_all,
            float* __restrict__ pre, unsigned* __restrict__ flags,
            const bf16* __restrict__ w_out_T, const float* __restrict__ b_out,
            float* __restrict__ out) {
  __shared__ char lds[65536];
  const int tid = threadIdx.x;
  const int lane = tid & 63;
  const int wv = tid >> 6;
  const int cl = lane & 15, g4 = lane >> 4;
  const int bid = blockIdx.x;
  const int in0 = lane * 16;
  const int dsw = in0 ^ ((wv & 7) << 4);

  auto stage = [&](char* dst, const char* srcbase, int rstr) {
    i32x4 v0 = ld16_sc(srcbase + (size_t)wv * rstr + in0);
    i32x4 v1 = ld16_sc(srcbase + (size_t)(wv + 8) * rstr + in0);
    wait_vm0();
    *(i32x4*)(dst + wv * 1024 + dsw) = v0;
    *(i32x4*)(dst + (wv + 8) * 1024 + dsw) = v1;
  };
  auto afrag = [&](const char* panel, int kk) {
    return *(const bf16x8s*)(panel + cl * 1024 + ((kk * 64 + g4 * 16) ^ ((cl & 7) << 4)));
  };
  auto poll8 = [&](const unsigned* f, unsigned tgt) {
    if (tid == 0) {
      for (;;) {
        i32x4 a = ld16_sc(f);
        i32x4 b = ld16_sc(f + 4);
        wait_vm0();                                  // #18 before the min chain
        if (min(min4u(a), min4u(b)) >= tgt) break;
        __builtin_amdgcn_s_sleep(1);
      }
    }
    __syncthreads();
    __builtin_amdgcn_sched_barrier(0);
  };
  auto poll32 = [&](const unsigned* f, unsigned tgt) {
    if (tid == 0) {
      for (;;) {
        i32x4 a0 = ld16_sc(f),      a1 = ld16_sc(f + 4),  a2 = ld16_sc(f + 8),
              a3 = ld16_sc(f + 12), a4 = ld16_sc(f + 16), a5 = ld16_sc(f + 20),
              a6 = ld16_sc(f + 24), a7 = ld16_sc(f + 28);
        wait_vm0();                                  // #18
        unsigned mn = min(min(min(min4u(a0), min4u(a1)), min(min4u(a2), min4u(a3))),
                          min(min(min4u(a4), min4u(a5)), min(min4u(a6), min4u(a7))));
        if (mn >= tgt) break;
        __builtin_amdgcn_s_sleep(1);
      }
    }
    __syncthreads();
    __builtin_amdgcn_sched_barrier(0);
  };

  if (bid < 64) {
    // ================= recurrence =================
    const int l = bid >> 5, wg5 = bid & 31, mt = wg5 & 3, ng = wg5 >> 2;
    const bool is_u = (wv >= 4);
    const int wsub = wv & 3;
    const int c = (ng * 4 + wsub) * 16 + cl;         // own col 0..511
    const int colA = is_u ? 512 + c : c;
    char* hp = lds;
    char* rp = lds + 16384;
    float* ul = (float*)(lds + 32768);
    char* rout = lds + 36864;
    char* hout = lds + 38912;

    unsigned* f_h  = flags + (l * 4 + mt) * 32;
    unsigned* f_rh = flags + 256 + (l * 4 + mt) * 32;
    unsigned* f_pre = flags + 512 + (l * 4 + mt) * 32;

    bf16* seql = l ? seq1 : seq0;
    bf16* rh = rh_all + (size_t)l * 64 * 512;
    float* prel = pre + (size_t)l * 4 * 1536 * 64;

    bf16x8s bwA[16];
    { const bf16* pa = w_ruh + (size_t)l * 1024 * 512 + (size_t)colA * NH + g4 * 8;
#pragma unroll
      for (int k = 0; k < 16; k++) bwA[k] = *(const bf16x8s*)(pa + k * 32); }
    bf16x8s bwB[16];
    float h_reg[4];
    if (!is_u) {
      const bf16* pb = w_hh + (size_t)l * 512 * 512 + (size_t)c * NH + g4 * 8;
#pragma unroll
      for (int k = 0; k < 16; k++) bwB[k] = *(const bf16x8s*)(pb + k * 32);
#pragma unroll
      for (int j = 0; j < 4; j++)
        h_reg[j] = h0f[(size_t)(mt * 16 + g4 * 4 + j) * NH + c];
    }

    for (int t = 0; t < NS; t++) {
      // combined poll: pre(t) ready AND (t>0) own h(t-1) complete
      if (tid == 0) {
        for (;;) {
          i32x4 p0 = ld16_sc(f_pre), p1 = ld16_sc(f_pre + 4), p2 = ld16_sc(f_pre + 8);
          i32x4 h0_, h1_;
          if (t) { h0_ = ld16_sc(f_h); h1_ = ld16_sc(f_h + 4); }
          wait_vm0();                                // #18
          unsigned mnp = min(min(min4u(p0), min4u(p1)), min4u(p2));
          bool ok = mnp >= (unsigned)(t + 1);
          if (t) ok = ok && (min(min4u(h0_), min4u(h1_)) >= (unsigned)t);
          if (ok) break;
          __builtin_amdgcn_s_sleep(1);
        }
      }
      __syncthreads();
      __builtin_amdgcn_sched_barrier(0);
      const int slot = t & 3;
      i32x4 pv1 = ld16_sc(prel + ((size_t)(slot * 1536 + colA) * 64 + mt * 16 + g4 * 4));
      i32x4 pv2 = {0, 0, 0, 0};
      if (!is_u)
        pv2 = ld16_sc(prel + ((size_t)(slot * 1536 + 1024 + c) * 64 + mt * 16 + g4 * 4));
      if (t == 0) stage(hp, (const char*)(h0b + (size_t)mt * 16 * NH), 1024);
      else        stage(hp, (const char*)seql + ((size_t)(mt * 16) * NS + (t - 1)) * 1024,
                        NS * 1024);
      __syncthreads();
      f32x4 pA = *(f32x4*)&pv1;
      f32x4 pB = *(f32x4*)&pv2;
      // phase 1
      {
        f32x4 acc = {0.f, 0.f, 0.f, 0.f};
#pragma unroll
        for (int kk = 0; kk < 16; kk++) acc = mfma16(afrag(hp, kk), bwA[kk], acc);
#pragma unroll
        for (int j = 0; j < 4; j++) {
          float gate = 1.f / (1.f + expf(-(acc[j] + pA[j])));
          if (is_u) {
            ul[(g4 * 4 + j) * 64 + wsub * 16 + cl] = gate;
          } else {
            bf16 o = f2bf(gate * h_reg[j]);
            *(unsigned short*)(rout + (g4 * 4 + j) * 128 + (wsub * 16 + cl) * 2)
              = *(unsigned short*)&o;
          }
        }
      }
      __syncthreads();
      { // publish rh
        if (tid < 128) {
          int row = tid >> 3, ch = tid & 7;
          i32x4 v = *(i32x4*)(rout + row * 128 + ch * 16);
          st16_sc((char*)rh + (((size_t)(mt * 16 + row)) * NH + ng * 64 + ch * 8) * 2, v);
        }
        wait_vm0();
        __syncthreads();
        if (tid == 0) stud_sc(f_rh + ng, (unsigned)(t + 1));
      }
      poll8(f_rh, (unsigned)(t + 1));
      stage(rp, (const char*)(rh + (size_t)mt * 16 * NH), 1024);
      __syncthreads();
      // phase 2
      if (!is_u) {
        f32x4 acc = {0.f, 0.f, 0.f, 0.f};
#pragma unroll
        for (int kk = 0; kk < 16; kk++) acc = mfma16(afrag(rp, kk), bwB[kk], acc);
#pragma unroll
        for (int j = 0; j < 4; j++) {
          float htil = tanhf(acc[j] + pB[j]);
          float u = ul[(g4 * 4 + j) * 64 + wsub * 16 + cl];
          float hnew = h_reg[j] * u + (1.f - u) * htil;
          h_reg[j] = hnew;
          bf16 hn = f2bf(hnew);
          *(unsigned short*)(hout + (g4 * 4 + j) * 128 + (wsub * 16 + cl) * 2)
            = *(unsigned short*)&hn;
        }
      }
      __syncthreads();
      { // publish h into seq[l]
        if (tid < 128) {
          int row = tid >> 3, ch = tid & 7;
          i32x4 v = *(i32x4*)(hout + row * 128 + ch * 16);
          st16_sc((char*)seql + (((size_t)(mt * 16 + row) * NS + t) * NH + ng * 64 + ch * 8) * 2, v);
        }
        wait_vm0();
        __syncthreads();
        if (tid == 0) {
          stud_sc(f_h + ng, (unsigned)(t + 1));
          if (l == 1) stud_sc(flags + 960 + mt * 8 + ng, (unsigned)(t + 1));  // compact
        }
      }
    }
  } else if (bid < 160) {
    // ================= x-part worker =================
    const int wb = bid - 64;                         // 0..95
    const int l = wb / 48, w48 = wb % 48, gg = w48 & 3, cw = w48 >> 2;  // cw 0..11
    char* xpan = lds;
    const int col = cw * 128 + wv * 16 + cl;         // 0..1535
    const bf16* xsrc = l ? seq0 : x0;
    float* prel = pre + (size_t)l * 4 * 1536 * 64;
    unsigned* f_h0g = flags + (0 * 4 + gg) * 32;
    unsigned* f_own = flags + (l * 4 + gg) * 32;
    unsigned* f_out = flags + 512 + (l * 4 + gg) * 32 + cw;

    bf16x8s wxw[16];
    { const bf16* pw = w_x + (size_t)l * 1536 * 512 + (size_t)col * 512 + g4 * 8;
#pragma unroll
      for (int kk = 0; kk < 16; kk++) wxw[kk] = *(const bf16x8s*)(pw + kk * 32); }
    const float bz = bias3[l * 1536 + col];

    for (int t = 0; t < NS; t++) {
      if (l == 1 || t >= 4) {
        if (tid == 0) {
          for (;;) {
            i32x4 a0 = {0,0,0,0}, a1 = {0,0,0,0}, b0 = {0,0,0,0}, b1 = {0,0,0,0};
            if (l == 1) { a0 = ld16_sc(f_h0g); a1 = ld16_sc(f_h0g + 4); }
            if (t >= 4) { b0 = ld16_sc(f_own); b1 = ld16_sc(f_own + 4); }
            wait_vm0();                              // #18
            bool ok = true;
            if (l == 1) ok = min(min4u(a0), min4u(a1)) >= (unsigned)(t + 1);
            if (t >= 4) ok = ok && (min(min4u(b0), min4u(b1)) >= (unsigned)(t - 3));
            if (ok) break;
            __builtin_amdgcn_s_sleep(1);
          }
        }
        __syncthreads();
        __builtin_amdgcn_sched_barrier(0);
      }
      stage(xpan, (const char*)xsrc + ((size_t)(gg * 16) * NS + t) * 1024, NS * 1024);
      __syncthreads();
      f32x4 acc = {0.f, 0.f, 0.f, 0.f};
#pragma unroll
      for (int kk = 0; kk < 16; kk++) acc = mfma16(afrag(xpan, kk), wxw[kk], acc);
      {
        f32x4 o;
#pragma unroll
        for (int j = 0; j < 4; j++) o[j] = acc[j] + bz;
        st16_sc(prel + ((size_t)((t & 3) * 1536 + col) * 64 + gg * 16 + g4 * 4),
                *(i32x4*)&o);
      }
      wait_vm0();
      __syncthreads();
      if (tid == 0) stud_sc(f_out, (unsigned)(t + 1));
    }
  } else {
    // ================= output-GEMM worker =================
    const int oj = bid - 160;                        // 0..95
    char* aslab = lds;                               // 64KB seq1 t-slab
    const int tile = oj * 8 + wv;                    // col-tile 0..767
    const int colb = tile * 16 + cl;                 // 0..12287
    bf16x8s bwO[16];
    { const bf16* pw = w_out_T + (size_t)colb * 512 + g4 * 8;
#pragma unroll
      for (int kk = 0; kk < 16; kk++) bwO[kk] = *(const bf16x8s*)(pw + kk * 32); }
    const float bz = (colb < NV) ? b_out[colb] : 0.f;
    unsigned* f1 = flags + 960;                      // compact l1 h flags (32 dw)

    for (int t = 0; t < NS; t++) {
      poll32(f1, (unsigned)(t + 1));
      { // stage seq1 t-slab: 64 rows x 1KB; wave per row per iter (coalesced)
        i32x4 vv[8];
        int rows[8], offs[8];
#pragma unroll
        for (int k8 = 0; k8 < 8; k8++) {
          int chunk = k8 * 512 + tid;
          rows[k8] = chunk >> 6;
          offs[k8] = (chunk & 63) * 16;
          vv[k8] = ld16_sc((const char*)seq1 + (size_t)t * 1024 +
                           (size_t)rows[k8] * (NS * 1024) + offs[k8]);
        }
        wait_vm0();
#pragma unroll
        for (int k8 = 0; k8 < 8; k8++)
          *(i32x4*)(aslab + rows[k8] * 1024 + (offs[k8] ^ ((rows[k8] & 7) << 4))) = vv[k8];
      }
      __syncthreads();
      f32x4 acc[4] = {};
#pragma unroll
      for (int kk = 0; kk < 16; kk++) {
#pragma unroll
        for (int mi = 0; mi < 4; mi++) {
          int row = mi * 16 + cl;
          bf16x8s a = *(const bf16x8s*)(aslab + row * 1024 +
                                        ((kk * 64 + g4 * 16) ^ ((row & 7) << 4)));
          acc[mi] = mfma16(a, bwO[kk], acc[mi]);
        }
      }
      if (colb < NV) {
#pragma unroll
        for (int mi = 0; mi < 4; mi++)
#pragma unroll
          for (int j = 0; j < 4; j++) {
            int b = mi * 16 + g4 * 4 + j;
            out[((size_t)b * NS + t) * NV + colb] = acc[mi][j] + bz;
          }
      }
      __syncthreads();                               // before next-t slab overwrite
    }
  }
}

extern "C" void kernel_launch(void* const* d_in, const int* in_sizes, int n_in,
                              void* d_out, int out_size, void* d_ws, size_t ws_size,
                              hipStream_t stream) {
  const int*   tokens = (const int*)d_in[0];
  const float* cnn    = (const float*)d_in[1];
  const float* emb    = (const float*)d_in[2];
  const float* w_in   = (const float*)d_in[3];
  const float* b_in   = (const float*)d_in[4];
  const float* w_r    = (const float*)d_in[5];
  const float* b_r    = (const float*)d_in[6];
  const float* w_u    = (const float*)d_in[7];
  const float* b_u    = (const float*)d_in[8];
  const float* w_h    = (const float*)d_in[9];
  const float* b_h    = (const float*)d_in[10];
  const float* w_out  = (const float*)d_in[11];
  const float* b_out  = (const float*)d_in[12];
  float* out = (float*)d_out;

  char* ws = (char*)d_ws;
  size_t off = 0;
  auto alloc = [&](size_t bytes) { char* p = ws + off; off += (bytes + 255) & ~(size_t)255; return p; };
  bf16*  x0      = (bf16*) alloc((size_t)2048 * 512 * 2);
  bf16*  seq0    = (bf16*) alloc((size_t)2048 * 512 * 2);
  bf16*  seq1    = (bf16*) alloc((size_t)2048 * 512 * 2);
  float* pre     = (float*)alloc((size_t)2 * 4 * 1536 * 64 * 4);   // [l][ring4][c][b]
  float* h0f     = (float*)alloc((size_t)64 * 512 * 4);
  bf16*  h0b     = (bf16*) alloc((size_t)64 * 512 * 2);
  bf16*  rh_all  = (bf16*) alloc((size_t)2 * 64 * 512 * 2);
  float* bias3   = (float*)alloc((size_t)2 * 1536 * 4);
  bf16*  cnn_b   = (bf16*) alloc((size_t)64 * 2048 * 2);
  bf16*  w_in_T  = (bf16*) alloc((size_t)512 * 2048 * 2);
  bf16*  w_ruh_T = (bf16*) alloc((size_t)2 * 1024 * 512 * 2);
  bf16*  w_hh_T  = (bf16*) alloc((size_t)2 * 512 * 512 * 2);
  bf16*  w_x_T   = (bf16*) alloc((size_t)2 * 1536 * 512 * 2);
  bf16*  w_out_T = (bf16*) alloc((size_t)12288 * 512 * 2);         // padded to 12288
  unsigned* flags = (unsigned*)alloc(4096);   // 1024 dwords
  (void)ws_size; (void)in_sizes; (void)n_in; (void)out_size;

  hipMemsetAsync(flags, 0, 4096, stream);
  hipMemsetAsync(w_out_T + (size_t)10000 * 512, 0, (size_t)(12288 - 10000) * 512 * 2, stream);

  k_embed<<<2048, 256, 0, stream>>>(tokens, emb, x0);
  k_cvt<<<512, 256, 0, stream>>>(cnn, cnn_b, 64 * 2048);
  k_transpose<<<dim3(16, 64), 256, 0, stream>>>(w_in, w_in_T, NF, NH);
  k_transpose12<<<dim3(16, 16, 12), 256, 0, stream>>>(w_r, w_u, w_h, w_ruh_T, w_hh_T, w_x_T);
  k_transpose<<<dim3(313, 16), 256, 0, stream>>>(w_out, w_out_T, 512, NV);
  k_bias3all<<<12, 256, 0, stream>>>(b_r, b_u, b_h, bias3);

  k_gemm_h0<<<32, 256, 0, stream>>>(cnn_b, w_in_T, b_in, h0f, h0b);

  k_gru2<<<256, 512, 0, stream>>>(w_ruh_T, w_hh_T, w_x_T, bias3, h0f, h0b,
                                  x0, seq0, seq1, rh_all, pre, flags,
                                  w_out_T, b_out, out);
}

// Round 14
// 238.863 us; speedup vs baseline: 3.1631x; 1.0917x over previous
//
#include <hip/hip_runtime.h>
#include <hip/hip_bf16.h>

typedef __hip_bfloat16 bf16;
typedef __attribute__((ext_vector_type(8))) short bf16x8s;
typedef __attribute__((ext_vector_type(4))) float f32x4;
typedef __attribute__((ext_vector_type(4))) int i32x4;

#define NB 64
#define NS 32
#define NV 10000
#define NE 512
#define NH 512
#define NF 2048
#define ND 1024

static __device__ __forceinline__ float bf2f(bf16 x) { return __bfloat162float(x); }
static __device__ __forceinline__ bf16 f2bf(float x) { return __float2bfloat16(x); }
static __device__ __forceinline__ short bfbits(float x) { bf16 h = f2bf(x); return *(short*)&h; }
static __device__ __forceinline__ f32x4 mfma16(bf16x8s a, bf16x8s b, f32x4 c) {
  return __builtin_amdgcn_mfma_f32_16x16x32_bf16(a, b, c, 0, 0, 0);
}

// ---- LLC-coherent (cross-XCD) accesses, bypassing per-XCD L1/L2 via sc0 sc1.
// Compiler does NOT track vmcnt — MUST wait_vm0() (waitcnt + sched_barrier,
// rule #18) before ANY use of results, including register-only VALU use.
static __device__ __forceinline__ i32x4 ld16_sc(const void* p) {
  i32x4 r;
  asm volatile("global_load_dwordx4 %0, %1, off sc0 sc1" : "=v"(r) : "v"(p) : "memory");
  return r;
}
static __device__ __forceinline__ void st16_sc(void* p, i32x4 v) {
  asm volatile("global_store_dwordx4 %0, %1, off sc0 sc1" :: "v"(p), "v"(v) : "memory");
}
static __device__ __forceinline__ void stud_sc(void* p, unsigned v) {
  asm volatile("global_store_dword %0, %1, off sc0 sc1" :: "v"(p), "v"(v) : "memory");
}
static __device__ __forceinline__ void wait_vm0() {
  asm volatile("s_waitcnt vmcnt(0)" ::: "memory");
  __builtin_amdgcn_sched_barrier(0);
}
static __device__ __forceinline__ unsigned min4u(i32x4 a) {
  return min(min((unsigned)a[0], (unsigned)a[1]), min((unsigned)a[2], (unsigned)a[3]));
}

// One 16x16 output tile per wave (cached path, plain GEMMs).
__device__ __forceinline__ f32x4 wave_tile16(const bf16* A, const bf16* BT,
                                             int lda, int K, int m0, int n0) {
  int lane = threadIdx.x & 63;
  int r = lane & 15, g = lane >> 4;
  const bf16* ap = A + (size_t)(m0 + r) * lda + g * 8;
  const bf16* bp = BT + (size_t)(n0 + r) * K + g * 8;
  f32x4 acc = {0.f, 0.f, 0.f, 0.f};
#pragma unroll 4
  for (int k = 0; k < K; k += 32) {
    bf16x8s a = *(const bf16x8s*)(ap + k);
    bf16x8s b = *(const bf16x8s*)(bp + k);
    acc = mfma16(a, b, acc);
  }
  return acc;
}

__global__ void k_cvt(const float* __restrict__ src, bf16* __restrict__ dst, int n) {
  int i = blockIdx.x * 256 + threadIdx.x;
  if (i < n) dst[i] = f2bf(src[i]);
}

__global__ void k_transpose(const float* __restrict__ src, bf16* __restrict__ dst,
                            int K, int N) {
  __shared__ float tile[32][33];
  int n0 = blockIdx.x * 32, k0 = blockIdx.y * 32;
  int tx = threadIdx.x & 31, ty = threadIdx.x >> 5;
  for (int i = ty; i < 32; i += 8) {
    int k = k0 + i, n = n0 + tx;
    tile[i][tx] = (k < K && n < N) ? src[(size_t)k * N + n] : 0.f;
  }
  __syncthreads();
  for (int i = ty; i < 32; i += 8) {
    int n = n0 + i, k = k0 + tx;
    if (n < N && k < K) dst[(size_t)n * K + k] = f2bf(tile[tx][i]);
  }
}

__global__ void k_transpose12(const float* __restrict__ w_r, const float* __restrict__ w_u,
                              const float* __restrict__ w_h, bf16* __restrict__ ruhT,
                              bf16* __restrict__ hhT, bf16* __restrict__ xT) {
  int z = blockIdx.z, l = z / 6, q = z % 6;
  const float* srcs[6] = {
    w_r + (size_t)l * ND * NH + (size_t)512 * NH,
    w_u + (size_t)l * ND * NH + (size_t)512 * NH,
    w_h + (size_t)l * ND * NH + (size_t)512 * NH,
    w_r + (size_t)l * ND * NH,
    w_u + (size_t)l * ND * NH,
    w_h + (size_t)l * ND * NH };
  bf16* dsts[6] = {
    ruhT + (size_t)l * 1024 * 512,
    ruhT + (size_t)l * 1024 * 512 + 512 * 512,
    hhT  + (size_t)l * 512 * 512,
    xT   + (size_t)l * 1536 * 512,
    xT   + (size_t)l * 1536 * 512 + 512 * 512,
    xT   + (size_t)l * 1536 * 512 + 1024 * 512 };
  const float* src = srcs[q];
  bf16* dst = dsts[q];
  __shared__ float tile[32][33];
  int n0 = blockIdx.x * 32, k0 = blockIdx.y * 32;
  int tx = threadIdx.x & 31, ty = threadIdx.x >> 5;
  for (int i = ty; i < 32; i += 8)
    tile[i][tx] = src[(size_t)(k0 + i) * NH + n0 + tx];
  __syncthreads();
  for (int i = ty; i < 32; i += 8)
    dst[(size_t)(n0 + i) * NH + k0 + tx] = f2bf(tile[tx][i]);
}

__global__ void k_bias3all(const float* __restrict__ br, const float* __restrict__ bu,
                           const float* __restrict__ bh, float* __restrict__ bias) {
  int i = blockIdx.x * 256 + threadIdx.x;
  if (i < 3072) {
    int l = i / 1536, c = i % 1536;
    const float* s = (c < 512) ? (br + l * 512 + c)
                   : (c < 1024 ? (bu + l * 512 + (c - 512)) : (bh + l * 512 + (c - 1024)));
    bias[i] = *s;
  }
}

// ---------------- h0 = cnn @ w_in + b_in, dual-store f32 + bf16 ----------------
__global__ void k_gemm_h0(const bf16* __restrict__ A, const bf16* __restrict__ BT,
                          const float* __restrict__ bias,
                          float* __restrict__ h0f, bf16* __restrict__ h0b) {
  int wid = blockIdx.x * 4 + (threadIdx.x >> 6);
  int mt = wid & 3, nt = wid >> 2;
  f32x4 acc = wave_tile16(A, BT, NF, NF, mt * 16, nt * 16);
  int lane = threadIdx.x & 63;
  int cl = lane & 15, g = lane >> 4;
  int col = nt * 16 + cl;
  float bv = bias[col];
#pragma unroll
  for (int j = 0; j < 4; j++) {
    int row = mt * 16 + g * 4 + j;
    float v = acc[j] + bv;
    h0f[(size_t)row * NH + col] = v;
    h0b[(size_t)row * NH + col] = f2bf(v);
  }
}

// ---------------- fused persistent: 2-layer GRU + x-workers + OUT-workers ----------------
// 256 WGs x 512 thr, 1 WG/CU. WGs 0..63: recurrence (R12 structure, proven).
// WGs 64..159: x-part workers; layer-0 workers gather emb[tokens] inline (no x0 buf).
// WGs 160..255: output workers (48 col-groups x 2 batch-halves): 32-row slabs,
// 2 tiles/wave register-resident (gathered directly from f32 w_out in prologue).
__global__ __launch_bounds__(512, 1)
void k_gru2(const bf16* __restrict__ w_ruh, const bf16* __restrict__ w_hh,
            const bf16* __restrict__ w_x, const float* __restrict__ bias3,
            const float* __restrict__ h0f, const bf16* __restrict__ h0b,
            const int* __restrict__ tokens, const float* __restrict__ emb,
            bf16* __restrict__ seq0, bf16* __restrict__ seq1,
            bf16* __restrict__ rh_all, float* __restrict__ pre,
            unsigned* __restrict__ flags, const float* __restrict__ w_out,
            const float* __restrict__ b_out, float* __restrict__ out) {
  __shared__ char lds[40960];
  const int tid = threadIdx.x;
  const int lane = tid & 63;
  const int wv = tid >> 6;
  const int cl = lane & 15, g4 = lane >> 4;
  const int bid = blockIdx.x;
  const int in0 = lane * 16;
  const int dsw = in0 ^ ((wv & 7) << 4);

  auto stage = [&](char* dst, const char* srcbase, int rstr) {
    i32x4 v0 = ld16_sc(srcbase + (size_t)wv * rstr + in0);
    i32x4 v1 = ld16_sc(srcbase + (size_t)(wv + 8) * rstr + in0);
    wait_vm0();
    *(i32x4*)(dst + wv * 1024 + dsw) = v0;
    *(i32x4*)(dst + (wv + 8) * 1024 + dsw) = v1;
  };
  auto afrag = [&](const char* panel, int kk) {
    return *(const bf16x8s*)(panel + cl * 1024 + ((kk * 64 + g4 * 16) ^ ((cl & 7) << 4)));
  };
  auto poll8 = [&](const unsigned* f, unsigned tgt) {
    if (tid == 0) {
      for (;;) {
        i32x4 a = ld16_sc(f);
        i32x4 b = ld16_sc(f + 4);
        wait_vm0();                                  // #18 before the min chain
        if (min(min4u(a), min4u(b)) >= tgt) break;
        __builtin_amdgcn_s_sleep(1);
      }
    }
    __syncthreads();
    __builtin_amdgcn_sched_barrier(0);
  };
  auto poll32 = [&](const unsigned* f, unsigned tgt) {
    if (tid == 0) {
      for (;;) {
        i32x4 a0 = ld16_sc(f),      a1 = ld16_sc(f + 4),  a2 = ld16_sc(f + 8),
              a3 = ld16_sc(f + 12), a4 = ld16_sc(f + 16), a5 = ld16_sc(f + 20),
              a6 = ld16_sc(f + 24), a7 = ld16_sc(f + 28);
        wait_vm0();                                  // #18
        unsigned mn = min(min(min(min4u(a0), min4u(a1)), min(min4u(a2), min4u(a3))),
                          min(min(min4u(a4), min4u(a5)), min(min4u(a6), min4u(a7))));
        if (mn >= tgt) break;
        __builtin_amdgcn_s_sleep(1);
      }
    }
    __syncthreads();
    __builtin_amdgcn_sched_barrier(0);
  };

  if (bid < 64) {
    // ================= recurrence =================
    const int l = bid >> 5, wg5 = bid & 31, mt = wg5 & 3, ng = wg5 >> 2;
    const bool is_u = (wv >= 4);
    const int wsub = wv & 3;
    const int c = (ng * 4 + wsub) * 16 + cl;
    const int colA = is_u ? 512 + c : c;
    char* hp = lds;
    char* rp = lds + 16384;
    float* ul = (float*)(lds + 32768);
    char* rout = lds + 36864;
    char* hout = lds + 38912;

    unsigned* f_h  = flags + (l * 4 + mt) * 32;
    unsigned* f_rh = flags + 256 + (l * 4 + mt) * 32;
    unsigned* f_pre = flags + 512 + (l * 4 + mt) * 32;

    bf16* seql = l ? seq1 : seq0;
    bf16* rh = rh_all + (size_t)l * 64 * 512;
    float* prel = pre + (size_t)l * 4 * 1536 * 64;

    bf16x8s bwA[16];
    { const bf16* pa = w_ruh + (size_t)l * 1024 * 512 + (size_t)colA * NH + g4 * 8;
#pragma unroll
      for (int k = 0; k < 16; k++) bwA[k] = *(const bf16x8s*)(pa + k * 32); }
    bf16x8s bwB[16];
    float h_reg[4];
    if (!is_u) {
      const bf16* pb = w_hh + (size_t)l * 512 * 512 + (size_t)c * NH + g4 * 8;
#pragma unroll
      for (int k = 0; k < 16; k++) bwB[k] = *(const bf16x8s*)(pb + k * 32);
#pragma unroll
      for (int j = 0; j < 4; j++)
        h_reg[j] = h0f[(size_t)(mt * 16 + g4 * 4 + j) * NH + c];
    }

    for (int t = 0; t < NS; t++) {
      if (tid == 0) {  // combined poll: pre(t) AND (t>0) h(t-1)
        for (;;) {
          i32x4 p0 = ld16_sc(f_pre), p1 = ld16_sc(f_pre + 4), p2 = ld16_sc(f_pre + 8);
          i32x4 h0_, h1_;
          if (t) { h0_ = ld16_sc(f_h); h1_ = ld16_sc(f_h + 4); }
          wait_vm0();                                // #18
          unsigned mnp = min(min(min4u(p0), min4u(p1)), min4u(p2));
          bool ok = mnp >= (unsigned)(t + 1);
          if (t) ok = ok && (min(min4u(h0_), min4u(h1_)) >= (unsigned)t);
          if (ok) break;
          __builtin_amdgcn_s_sleep(1);
        }
      }
      __syncthreads();
      __builtin_amdgcn_sched_barrier(0);
      const int slot = t & 3;
      i32x4 pv1 = ld16_sc(prel + ((size_t)(slot * 1536 + colA) * 64 + mt * 16 + g4 * 4));
      i32x4 pv2 = {0, 0, 0, 0};
      if (!is_u)
        pv2 = ld16_sc(prel + ((size_t)(slot * 1536 + 1024 + c) * 64 + mt * 16 + g4 * 4));
      if (t == 0) stage(hp, (const char*)(h0b + (size_t)mt * 16 * NH), 1024);
      else        stage(hp, (const char*)seql + ((size_t)(mt * 16) * NS + (t - 1)) * 1024,
                        NS * 1024);
      __syncthreads();
      f32x4 pA = *(f32x4*)&pv1;
      f32x4 pB = *(f32x4*)&pv2;
      // phase 1
      {
        f32x4 acc = {0.f, 0.f, 0.f, 0.f};
#pragma unroll
        for (int kk = 0; kk < 16; kk++) acc = mfma16(afrag(hp, kk), bwA[kk], acc);
#pragma unroll
        for (int j = 0; j < 4; j++) {
          float gate = 1.f / (1.f + expf(-(acc[j] + pA[j])));
          if (is_u) {
            ul[(g4 * 4 + j) * 64 + wsub * 16 + cl] = gate;
          } else {
            bf16 o = f2bf(gate * h_reg[j]);
            *(unsigned short*)(rout + (g4 * 4 + j) * 128 + (wsub * 16 + cl) * 2)
              = *(unsigned short*)&o;
          }
        }
      }
      __syncthreads();
      { // publish rh
        if (tid < 128) {
          int row = tid >> 3, ch = tid & 7;
          i32x4 v = *(i32x4*)(rout + row * 128 + ch * 16);
          st16_sc((char*)rh + (((size_t)(mt * 16 + row)) * NH + ng * 64 + ch * 8) * 2, v);
        }
        wait_vm0();
        __syncthreads();
        if (tid == 0) stud_sc(f_rh + ng, (unsigned)(t + 1));
      }
      poll8(f_rh, (unsigned)(t + 1));
      stage(rp, (const char*)(rh + (size_t)mt * 16 * NH), 1024);
      __syncthreads();
      // phase 2
      if (!is_u) {
        f32x4 acc = {0.f, 0.f, 0.f, 0.f};
#pragma unroll
        for (int kk = 0; kk < 16; kk++) acc = mfma16(afrag(rp, kk), bwB[kk], acc);
#pragma unroll
        for (int j = 0; j < 4; j++) {
          float htil = tanhf(acc[j] + pB[j]);
          float u = ul[(g4 * 4 + j) * 64 + wsub * 16 + cl];
          float hnew = h_reg[j] * u + (1.f - u) * htil;
          h_reg[j] = hnew;
          bf16 hn = f2bf(hnew);
          *(unsigned short*)(hout + (g4 * 4 + j) * 128 + (wsub * 16 + cl) * 2)
            = *(unsigned short*)&hn;
        }
      }
      __syncthreads();
      { // publish h into seq[l]
        if (tid < 128) {
          int row = tid >> 3, ch = tid & 7;
          i32x4 v = *(i32x4*)(hout + row * 128 + ch * 16);
          st16_sc((char*)seql + (((size_t)(mt * 16 + row) * NS + t) * NH + ng * 64 + ch * 8) * 2, v);
        }
        wait_vm0();
        __syncthreads();
        if (tid == 0) {
          stud_sc(f_h + ng, (unsigned)(t + 1));
          if (l == 1) stud_sc(flags + 960 + mt * 8 + ng, (unsigned)(t + 1));
        }
      }
    }
  } else if (bid < 160) {
    // ================= x-part worker =================
    const int wb = bid - 64;
    const int l = wb / 48, w48 = wb % 48, gg = w48 & 3, cw = w48 >> 2;
    char* xpan = lds;
    const int col = cw * 128 + wv * 16 + cl;
    float* prel = pre + (size_t)l * 4 * 1536 * 64;
    unsigned* f_h0g = flags + (0 * 4 + gg) * 32;
    unsigned* f_own = flags + (l * 4 + gg) * 32;
    unsigned* f_out = flags + 512 + (l * 4 + gg) * 32 + cw;

    bf16x8s wxw[16];
    { const bf16* pw = w_x + (size_t)l * 1536 * 512 + (size_t)col * 512 + g4 * 8;
#pragma unroll
      for (int kk = 0; kk < 16; kk++) wxw[kk] = *(const bf16x8s*)(pw + kk * 32); }
    const float bz = bias3[l * 1536 + col];

    for (int t = 0; t < NS; t++) {
      if (l == 1 || t >= 4) {
        if (tid == 0) {
          for (;;) {
            i32x4 a0 = {0,0,0,0}, a1 = {0,0,0,0}, b0 = {0,0,0,0}, b1 = {0,0,0,0};
            if (l == 1) { a0 = ld16_sc(f_h0g); a1 = ld16_sc(f_h0g + 4); }
            if (t >= 4) { b0 = ld16_sc(f_own); b1 = ld16_sc(f_own + 4); }
            wait_vm0();                              // #18
            bool ok = true;
            if (l == 1) ok = min(min4u(a0), min4u(a1)) >= (unsigned)(t + 1);
            if (t >= 4) ok = ok && (min(min4u(b0), min4u(b1)) >= (unsigned)(t - 3));
            if (ok) break;
            __builtin_amdgcn_s_sleep(1);
          }
        }
        __syncthreads();
        __builtin_amdgcn_sched_barrier(0);
      }
      if (l == 0) {
        // inline embedding gather+convert: slab row r -> emb[tokens[gg*16+r][t]]
#pragma unroll
        for (int rr = 0; rr < 2; rr++) {
          int r = wv + rr * 8;
          int tok = tokens[(gg * 16 + r) * NS + t];
          const float* ep = emb + (size_t)tok * NE + lane * 8;
          f32x4 v0 = *(const f32x4*)ep;
          f32x4 v1 = *(const f32x4*)(ep + 4);
          bf16x8s o;
#pragma unroll
          for (int j = 0; j < 4; j++) { o[j] = bfbits(v0[j]); o[4 + j] = bfbits(v1[j]); }
          *(i32x4*)(xpan + r * 1024 + dsw) = *(i32x4*)&o;
        }
      } else {
        stage(xpan, (const char*)seq0 + ((size_t)(gg * 16) * NS + t) * 1024, NS * 1024);
      }
      __syncthreads();
      f32x4 acc = {0.f, 0.f, 0.f, 0.f};
#pragma unroll
      for (int kk = 0; kk < 16; kk++) acc = mfma16(afrag(xpan, kk), wxw[kk], acc);
      {
        f32x4 o;
#pragma unroll
        for (int j = 0; j < 4; j++) o[j] = acc[j] + bz;
        st16_sc(prel + ((size_t)((t & 3) * 1536 + col) * 64 + gg * 16 + g4 * 4),
                *(i32x4*)&o);
      }
      wait_vm0();
      __syncthreads();
      if (tid == 0) stud_sc(f_out, (unsigned)(t + 1));
    }
  } else {
    // ================= output-GEMM worker =================
    const int oj = bid - 160;                        // 0..95
    const int bh = oj & 1, cg = oj >> 1;             // batch half, col-group 0..47
    char* aslab = lds;                               // 32KB seq1 half-slab
    const int colb0 = (cg * 16 + wv * 2) * 16 + cl;  // tile 0
    const int colb1 = colb0 + 16;                    // tile 1
    // gather B-fragments directly from f32 w_out [512][10000] (one-time)
    bf16x8s bw0[16], bw1[16];
#pragma unroll
    for (int kk = 0; kk < 16; kk++) {
      bf16x8s f0, f1;
#pragma unroll
      for (int jj = 0; jj < 8; jj++) {
        int k = kk * 32 + g4 * 8 + jj;
        f0[jj] = (colb0 < NV) ? bfbits(w_out[(size_t)k * NV + colb0]) : (short)0;
        f1[jj] = (colb1 < NV) ? bfbits(w_out[(size_t)k * NV + colb1]) : (short)0;
      }
      bw0[kk] = f0; bw1[kk] = f1;
    }
    const float bz0 = (colb0 < NV) ? b_out[colb0] : 0.f;
    const float bz1 = (colb1 < NV) ? b_out[colb1] : 0.f;
    unsigned* f1f = flags + 960;                     // compact l1 h flags

    for (int t = 0; t < NS; t++) {
      poll32(f1f, (unsigned)(t + 1));
      { // stage 32-row half-slab: 4 rounds x 8KB
        i32x4 vv[4];
        int rows[4], offs[4];
#pragma unroll
        for (int k4 = 0; k4 < 4; k4++) {
          int chunk = k4 * 512 + tid;
          rows[k4] = chunk >> 6;                     // 0..31
          offs[k4] = (chunk & 63) * 16;
          vv[k4] = ld16_sc((const char*)seq1 +
                           ((size_t)(bh * 32 + rows[k4]) * NS + t) * 1024 + offs[k4]);
        }
        wait_vm0();
#pragma unroll
        for (int k4 = 0; k4 < 4; k4++)
          *(i32x4*)(aslab + rows[k4] * 1024 + (offs[k4] ^ ((rows[k4] & 7) << 4))) = vv[k4];
      }
      __syncthreads();
      f32x4 acc00 = {}, acc01 = {}, acc10 = {}, acc11 = {};
#pragma unroll
      for (int kk = 0; kk < 16; kk++) {
        int r0 = cl, r1 = 16 + cl;
        bf16x8s a0 = *(const bf16x8s*)(aslab + r0 * 1024 +
                                       ((kk * 64 + g4 * 16) ^ ((r0 & 7) << 4)));
        bf16x8s a1 = *(const bf16x8s*)(aslab + r1 * 1024 +
                                       ((kk * 64 + g4 * 16) ^ ((r1 & 7) << 4)));
        acc00 = mfma16(a0, bw0[kk], acc00);
        acc01 = mfma16(a0, bw1[kk], acc01);
        acc10 = mfma16(a1, bw0[kk], acc10);
        acc11 = mfma16(a1, bw1[kk], acc11);
      }
#pragma unroll
      for (int j = 0; j < 4; j++) {
        int b0r = bh * 32 + g4 * 4 + j;              // mi=0
        int b1r = b0r + 16;                          // mi=1
        if (colb0 < NV) {
          out[((size_t)b0r * NS + t) * NV + colb0] = acc00[j] + bz0;
          out[((size_t)b1r * NS + t) * NV + colb0] = acc10[j] + bz0;
        }
        if (colb1 < NV) {
          out[((size_t)b0r * NS + t) * NV + colb1] = acc01[j] + bz1;
          out[((size_t)b1r * NS + t) * NV + colb1] = acc11[j] + bz1;
        }
      }
      __syncthreads();                               // before next-t slab overwrite
    }
  }
}

extern "C" void kernel_launch(void* const* d_in, const int* in_sizes, int n_in,
                              void* d_out, int out_size, void* d_ws, size_t ws_size,
                              hipStream_t stream) {
  const int*   tokens = (const int*)d_in[0];
  const float* cnn    = (const float*)d_in[1];
  const float* emb    = (const float*)d_in[2];
  const float* w_in   = (const float*)d_in[3];
  const float* b_in   = (const float*)d_in[4];
  const float* w_r    = (const float*)d_in[5];
  const float* b_r    = (const float*)d_in[6];
  const float* w_u    = (const float*)d_in[7];
  const float* b_u    = (const float*)d_in[8];
  const float* w_h    = (const float*)d_in[9];
  const float* b_h    = (const float*)d_in[10];
  const float* w_out  = (const float*)d_in[11];
  const float* b_out  = (const float*)d_in[12];
  float* out = (float*)d_out;

  char* ws = (char*)d_ws;
  size_t off = 0;
  auto alloc = [&](size_t bytes) { char* p = ws + off; off += (bytes + 255) & ~(size_t)255; return p; };
  bf16*  seq0    = (bf16*) alloc((size_t)2048 * 512 * 2);
  bf16*  seq1    = (bf16*) alloc((size_t)2048 * 512 * 2);
  float* pre     = (float*)alloc((size_t)2 * 4 * 1536 * 64 * 4);   // [l][ring4][c][b]
  float* h0f     = (float*)alloc((size_t)64 * 512 * 4);
  bf16*  h0b     = (bf16*) alloc((size_t)64 * 512 * 2);
  bf16*  rh_all  = (bf16*) alloc((size_t)2 * 64 * 512 * 2);
  float* bias3   = (float*)alloc((size_t)2 * 1536 * 4);
  bf16*  cnn_b   = (bf16*) alloc((size_t)64 * 2048 * 2);
  bf16*  w_in_T  = (bf16*) alloc((size_t)512 * 2048 * 2);
  bf16*  w_ruh_T = (bf16*) alloc((size_t)2 * 1024 * 512 * 2);
  bf16*  w_hh_T  = (bf16*) alloc((size_t)2 * 512 * 512 * 2);
  bf16*  w_x_T   = (bf16*) alloc((size_t)2 * 1536 * 512 * 2);
  unsigned* flags = (unsigned*)alloc(4096);   // 1024 dwords
  (void)ws_size; (void)in_sizes; (void)n_in; (void)out_size;

  hipMemsetAsync(flags, 0, 4096, stream);

  k_cvt<<<512, 256, 0, stream>>>(cnn, cnn_b, 64 * 2048);
  k_transpose<<<dim3(16, 64), 256, 0, stream>>>(w_in, w_in_T, NF, NH);
  k_transpose12<<<dim3(16, 16, 12), 256, 0, stream>>>(w_r, w_u, w_h, w_ruh_T, w_hh_T, w_x_T);
  k_bias3all<<<12, 256, 0, stream>>>(b_r, b_u, b_h, bias3);

  k_gemm_h0<<<32, 256, 0, stream>>>(cnn_b, w_in_T, b_in, h0f, h0b);

  k_gru2<<<256, 512, 0, stream>>>(w_ruh_T, w_hh_T, w_x_T, bias3, h0f, h0b,
                                  tokens, emb, seq0, seq1, rh_all, pre, flags,
                                  w_out, b_out, out);
}